// Round 9
// baseline (3740.009 us; speedup 1.0000x reference)
//
#include <hip/hip_runtime.h>
#include <hip/hip_bf16.h>
#include <hip/hip_cooperative_groups.h>
#include <math.h>

namespace cg = cooperative_groups;

using u16 = unsigned short;
using s8v = __attribute__((ext_vector_type(8))) short;   // 8 bf16 (4 VGPRs) - MFMA A/B frag
using s4v = __attribute__((ext_vector_type(4))) short;   // 4 bf16
using f4v = __attribute__((ext_vector_type(4))) float;   // MFMA C/D frag

__device__ __forceinline__ float b2f(u16 x) {
    unsigned int u = ((unsigned int)x) << 16;
    return __uint_as_float(u);
}
__device__ __forceinline__ u16 f2b(float f) {
    unsigned int x = __float_as_uint(f);
    unsigned int r = x + 0x7fffu + ((x >> 16) & 1u);   // RNE
    return (u16)(r >> 16);
}

// async global->LDS, 16B per lane; lds base wave-uniform (lane scatter = lane*16)
__device__ __forceinline__ void a16(u16* lds, const u16* g) {
    __builtin_amdgcn_global_load_lds((__attribute__((address_space(1))) void*)g,
                                     (__attribute__((address_space(3))) void*)lds,
                                     16, 0, 0);
}

// ---------------- reductions ----------------
__device__ __forceinline__ float block_sum(float v, float* buf) {
    int t = threadIdx.x;
    buf[t] = v; __syncthreads();
    for (int s = 128; s > 0; s >>= 1) {
        if (t < s) buf[t] += buf[t + s];
        __syncthreads();
    }
    float r = buf[0];
    __syncthreads();
    return r;
}

__device__ __forceinline__ float wave_sum(float v) {
#pragma unroll
    for (int off = 32; off; off >>= 1) v += __shfl_xor(v, off, 64);
    return v;
}

__device__ __forceinline__ void block_atomic4(float wval, float* slot) {
    __shared__ float wb[4];
    int lane = threadIdx.x & 63, wv = threadIdx.x >> 6;
    if (lane == 0) wb[wv] = wval;
    __syncthreads();
    if (threadIdx.x == 0) atomicAdd(slot, wb[0] + wb[1] + wb[2] + wb[3]);
    __syncthreads();
}

// ---------------- GEMM core ----------------
#define TBM 128
#define TBN 128
#define TBK 32

// single-problem GEMM. EPI: 1 -> bf16 C, 3 -> atomicAdd fp32 C (split-K via blockIdx.z)
template<int EPI>
__global__ __launch_bounds__(256)
void gemm_bt(const u16* __restrict__ A, const u16* __restrict__ B,
             float* __restrict__ Cf, u16* __restrict__ Cb,
             int M, int N, int K, int ld, float alpha)
{
    __shared__ __align__(16) u16 As[TBM * TBK];
    __shared__ __align__(16) u16 Bs[TBN * TBK];

    const int tid  = threadIdx.x;
    const int lane = tid & 63;
    const int wave = tid >> 6;
    const int wm   = (wave >> 1) * 64;
    const int wn   = (wave & 1) * 64;
    const int l16  = lane & 15;
    const int q4   = lane >> 4;
    const size_t row0 = (size_t)blockIdx.y * TBM;
    const size_t col0 = (size_t)blockIdx.x * TBN;
    const int kOff = blockIdx.z * K;

    f4v acc[4][4];
#pragma unroll
    for (int mt = 0; mt < 4; ++mt)
#pragma unroll
        for (int nt = 0; nt < 4; ++nt)
#pragma unroll
            for (int r = 0; r < 4; ++r)
                acc[mt][nt][r] = 0.f;

    const int ar0 = wave * 32 + (lane >> 2);
    const int ar1 = ar0 + 16;
    const int akk = (lane & 3) * 8;
    const u16* gA0 = A + (row0 + ar0) * ld + kOff + akk;
    const u16* gA1 = A + (row0 + ar1) * ld + kOff + akk;
    const u16* gB0 = B + (col0 + ar0) * ld + kOff + akk;
    const u16* gB1 = B + (col0 + ar1) * ld + kOff + akk;
    u16* lA0 = As + wave * 1024;
    u16* lA1 = As + wave * 1024 + 512;
    u16* lB0 = Bs + wave * 1024;
    u16* lB1 = Bs + wave * 1024 + 512;

    for (int k0 = 0; k0 < K; k0 += TBK) {
        __syncthreads();
        a16(lA0, gA0 + k0);
        a16(lA1, gA1 + k0);
        a16(lB0, gB0 + k0);
        a16(lB1, gB1 + k0);
        __syncthreads();

        s8v af[4], bfr[4];
#pragma unroll
        for (int mt = 0; mt < 4; ++mt)
            af[mt] = *(const s8v*)(As + (wm + mt * 16 + l16) * TBK + q4 * 8);
#pragma unroll
        for (int nt = 0; nt < 4; ++nt)
            bfr[nt] = *(const s8v*)(Bs + (wn + nt * 16 + l16) * TBK + q4 * 8);
#pragma unroll
        for (int mt = 0; mt < 4; ++mt)
#pragma unroll
            for (int nt = 0; nt < 4; ++nt)
                acc[mt][nt] = __builtin_amdgcn_mfma_f32_16x16x32_bf16(af[mt], bfr[nt], acc[mt][nt], 0, 0, 0);
    }

#pragma unroll
    for (int mt = 0; mt < 4; ++mt)
#pragma unroll
        for (int nt = 0; nt < 4; ++nt)
#pragma unroll
            for (int r = 0; r < 4; ++r) {
                size_t row = row0 + wm + mt * 16 + q4 * 4 + r;
                size_t col = col0 + wn + nt * 16 + l16;
                float v = acc[mt][nt][r] * alpha;
                if (EPI == 1) Cb[row * (size_t)N + col] = f2b(v);
                else          atomicAdd(&Cf[row * (size_t)N + col], v);
            }
}

// ---------------- generalized batched GEMM ----------------
// EPI: 0 -> store fp32 (z=1), 1 -> store bf16 (z=1),
//      2 -> dot epilogue: atomicAdd(slot, sum(C .* W^T)) with W[col*WL+row],
//      3 -> atomicAdd fp32 C (split-K),
//      4 -> store fp32 to per-slice buffer Cf + z*M*N (split-K, no atomics)
struct BGN {
    const u16* A; const u16* B;
    float* Cf; u16* Cb;
    const u16* W; float* slot;
    int M, N, Kc, ld, WL, tN, tEnd;
};
struct BGNArgs { BGN d[6]; int n; float alpha; };

template<int EPI>
__global__ __launch_bounds__(256)
void bgemmN(BGNArgs g)
{
    __shared__ __align__(16) u16 As[TBM * TBK];
    __shared__ __align__(16) u16 Bs[TBN * TBK];

    int bi = 0;
    while (bi < g.n - 1 && (int)blockIdx.x >= g.d[bi].tEnd) ++bi;
    const BGN& d = g.d[bi];
    const int tStart = bi ? g.d[bi - 1].tEnd : 0;
    const int local = blockIdx.x - tStart;
    const int tm = local / d.tN;
    const int tn = local - tm * d.tN;

    const int tid  = threadIdx.x;
    const int lane = tid & 63;
    const int wave = tid >> 6;
    const int wm   = (wave >> 1) * 64;
    const int wn   = (wave & 1) * 64;
    const int l16  = lane & 15;
    const int q4   = lane >> 4;
    const size_t row0 = (size_t)tm * TBM;
    const size_t col0 = (size_t)tn * TBN;
    const int kOff = blockIdx.y * d.Kc;
    const int ld = d.ld;

    f4v acc[4][4];
#pragma unroll
    for (int mt = 0; mt < 4; ++mt)
#pragma unroll
        for (int nt = 0; nt < 4; ++nt)
#pragma unroll
            for (int r = 0; r < 4; ++r)
                acc[mt][nt][r] = 0.f;

    const int ar0 = wave * 32 + (lane >> 2);
    const int ar1 = ar0 + 16;
    const int akk = (lane & 3) * 8;
    const u16* gA0 = d.A + (row0 + ar0) * ld + kOff + akk;
    const u16* gA1 = d.A + (row0 + ar1) * ld + kOff + akk;
    const u16* gB0 = d.B + (col0 + ar0) * ld + kOff + akk;
    const u16* gB1 = d.B + (col0 + ar1) * ld + kOff + akk;
    u16* lA0 = As + wave * 1024;
    u16* lA1 = As + wave * 1024 + 512;
    u16* lB0 = Bs + wave * 1024;
    u16* lB1 = Bs + wave * 1024 + 512;

    for (int k0 = 0; k0 < d.Kc; k0 += TBK) {
        __syncthreads();
        a16(lA0, gA0 + k0);
        a16(lA1, gA1 + k0);
        a16(lB0, gB0 + k0);
        a16(lB1, gB1 + k0);
        __syncthreads();

        s8v af[4], bfr[4];
#pragma unroll
        for (int mt = 0; mt < 4; ++mt)
            af[mt] = *(const s8v*)(As + (wm + mt * 16 + l16) * TBK + q4 * 8);
#pragma unroll
        for (int nt = 0; nt < 4; ++nt)
            bfr[nt] = *(const s8v*)(Bs + (wn + nt * 16 + l16) * TBK + q4 * 8);
#pragma unroll
        for (int mt = 0; mt < 4; ++mt)
#pragma unroll
            for (int nt = 0; nt < 4; ++nt)
                acc[mt][nt] = __builtin_amdgcn_mfma_f32_16x16x32_bf16(af[mt], bfr[nt], acc[mt][nt], 0, 0, 0);
    }

    if (EPI == 2) {
        float local2 = 0.f;
#pragma unroll
        for (int mt = 0; mt < 4; ++mt)
#pragma unroll
            for (int nt = 0; nt < 4; ++nt)
#pragma unroll
                for (int r = 0; r < 4; ++r) {
                    size_t row = row0 + wm + mt * 16 + q4 * 4 + r;
                    size_t col = col0 + wn + nt * 16 + l16;
                    local2 += acc[mt][nt][r] * b2f(d.W[col * (size_t)d.WL + row]);
                }
        __shared__ float red[256];
        float tot = block_sum(local2 * g.alpha, red);
        if (tid == 0) atomicAdd(d.slot, tot);
    } else {
        float* Cs = (EPI == 4) ? d.Cf + (size_t)blockIdx.y * d.M * d.N : d.Cf;
#pragma unroll
        for (int mt = 0; mt < 4; ++mt)
#pragma unroll
            for (int nt = 0; nt < 4; ++nt)
#pragma unroll
                for (int r = 0; r < 4; ++r) {
                    size_t row = row0 + wm + mt * 16 + q4 * 4 + r;
                    size_t col = col0 + wn + nt * 16 + l16;
                    float v = acc[mt][nt][r] * g.alpha;
                    if (EPI == 0)      d.Cf[row * (size_t)d.N + col] = v;
                    else if (EPI == 1) d.Cb[row * (size_t)d.N + col] = f2b(v);
                    else if (EPI == 4) Cs[row * (size_t)d.N + col] = v;
                    else               atomicAdd(&d.Cf[row * (size_t)d.N + col], v);
                }
    }
}

// ---------------- batched rownorm ----------------
struct RN { const float* in; u16* out; int C; int rEnd; };
struct RNArgs { RN d[8]; int n; };

__global__ __launch_bounds__(256)
void rownorm_batch(RNArgs a) {
    int gw = (blockIdx.x * 256 + threadIdx.x) >> 6;
    int lane = threadIdx.x & 63;
    int i = 0;
    while (i < a.n - 1 && gw >= a.d[i].rEnd) ++i;
    if (gw >= a.d[i].rEnd) return;
    int row = gw - (i ? a.d[i - 1].rEnd : 0);
    int C = a.d[i].C;
    const float4* r4 = (const float4*)(a.d[i].in + (size_t)row * C);
    int nv = C >> 2;
    float ss = 0.f;
    for (int c = lane; c < nv; c += 64) {
        float4 v = r4[c];
        ss += v.x * v.x + v.y * v.y + v.z * v.z + v.w * v.w;
    }
    ss = wave_sum(ss);
    float inv = 1.f / fmaxf(sqrtf(ss), 1e-8f);
    s4v* o4 = (s4v*)(a.d[i].out + (size_t)row * C);
    for (int c = lane; c < nv; c += 64) {
        float4 v = r4[c];
        s4v o;
        o[0] = (short)f2b(v.x * inv); o[1] = (short)f2b(v.y * inv);
        o[2] = (short)f2b(v.z * inv); o[3] = (short)f2b(v.w * inv);
        o4[c] = o;
    }
}

__global__ __launch_bounds__(256)
void mahal_w(const u16* __restrict__ Xh, const float* __restrict__ XS,
             u16* __restrict__ out, int nrows, int C) {
    int row = (blockIdx.x * 256 + threadIdx.x) >> 6;
    int lane = threadIdx.x & 63;
    if (row >= nrows) return;
    const s4v* x4 = (const s4v*)(Xh + (size_t)row * C);
    const float4* s4 = (const float4*)(XS + (size_t)row * C);
    int nv = C >> 2;
    float s = 0.f;
    for (int c = lane; c < nv; c += 64) {
        s4v x = x4[c]; float4 v = s4[c];
        s += b2f((u16)x[0]) * v.x + b2f((u16)x[1]) * v.y
           + b2f((u16)x[2]) * v.z + b2f((u16)x[3]) * v.w;
    }
    s = wave_sum(s);
    float inv = 1.f / fmaxf(sqrtf(fmaxf(s, 0.f)), 1e-8f);
    s4v* o4 = (s4v*)(out + (size_t)row * C);
    for (int c = lane; c < nv; c += 64) {
        s4v x = x4[c], o;
#pragma unroll
        for (int k = 0; k < 4; ++k) o[k] = (short)f2b(b2f((u16)x[k]) * inv);
        o4[c] = o;
    }
}

// ---------------- batched 32x32 transpose (optional per-input-row scale) ------
struct TP { const u16* in; u16* out; int R, C, tC, tEnd; const float* s; };
struct TPArgs { TP d[6]; int n; };

__global__ __launch_bounds__(256)
void transpose_batch(TPArgs a) {
    __shared__ u16 tile[32][33];
    int t = blockIdx.x;
    int i = 0;
    while (i < a.n - 1 && t >= a.d[i].tEnd) ++i;
    int local = t - (i ? a.d[i - 1].tEnd : 0);
    const TP& d = a.d[i];
    int ty = local / d.tC, tx = local - ty * d.tC;
    int bx = tx * 32, by = ty * 32;
    int lx = threadIdx.x & 31;
    int lyy = threadIdx.x >> 5;
    for (int r = lyy; r < 32; r += 8)
        tile[r][lx] = d.in[(size_t)(by + r) * d.C + bx + lx];
    __syncthreads();
    for (int r = lyy; r < 32; r += 8) {
        u16 val = tile[lx][r];
        if (d.s) val = f2b(b2f(val) * d.s[by + lx]);
        d.out[(size_t)(bx + r) * d.R + by + lx] = val;
    }
}

__global__ __launch_bounds__(256)
void cast_f2b(const float* __restrict__ in, u16* __restrict__ out, int n) {
    for (int i = blockIdx.x * 256 + threadIdx.x; i < n; i += gridDim.x * 256)
        out[i] = f2b(in[i]);
}

// ---------------- sinkhorn row pass (no-max sum-exp; logits bounded) ----------
__device__ __forceinline__ float row_sumexp(const u16* __restrict__ rowp,
                                            const float* __restrict__ vin,
                                            int ny, float scale, int lane) {
    const s8v* r8 = (const s8v*)rowp;
    const float4* v4 = (const float4*)vin;
    int nv = ny >> 3;
    float s = 0.f;
    for (int c = lane; c < nv; c += 64) {
        s8v v8 = r8[c];
        float4 va = v4[c * 2], vb = v4[c * 2 + 1];
        s += __expf(b2f((u16)v8[0]) * scale + va.x);
        s += __expf(b2f((u16)v8[1]) * scale + va.y);
        s += __expf(b2f((u16)v8[2]) * scale + va.z);
        s += __expf(b2f((u16)v8[3]) * scale + va.w);
        s += __expf(b2f((u16)v8[4]) * scale + vb.x);
        s += __expf(b2f((u16)v8[5]) * scale + vb.y);
        s += __expf(b2f((u16)v8[6]) * scale + vb.z);
        s += __expf(b2f((u16)v8[7]) * scale + vb.w);
    }
    return wave_sum(s);
}

// one half-iteration pass over 3 problems; slot = virtual row group [0,2560)
__device__ __forceinline__ void tri_pass(int s, int wv, int lane,
                                         const u16* C1, const float* v1, float* u1,
                                         const u16* C2, const float* v2, float* u2,
                                         const u16* C3, const float* v3, float* u3,
                                         float scale, float lm12, float lm3) {
    int gw = s * 4 + wv;
    if (gw < 4096) {
        float t = row_sumexp(C1 + (size_t)gw * 4096, v1, 4096, scale, lane);
        if (lane == 0) u1[gw] = lm12 - __logf(t);
    } else if (gw < 8192) {
        int r = gw - 4096;
        float t = row_sumexp(C2 + (size_t)r * 4096, v2, 4096, scale, lane);
        if (lane == 0) u2[r] = lm12 - __logf(t);
    } else if (gw < 10240) {
        int r = gw - 8192;
        float t = row_sumexp(C3 + (size_t)r * 2048, v3, 2048, scale, lane);
        if (lane == 0) u3[r] = lm3 - __logf(t);
    }
}

// dispatch version (fallback path)
__global__ __launch_bounds__(256)
void row_lse_tri(const u16* __restrict__ C1, const float* __restrict__ v1, float* __restrict__ u1,
                 const u16* __restrict__ C2, const float* __restrict__ v2, float* __restrict__ u2,
                 const u16* __restrict__ C3, const float* __restrict__ v3, float* __restrict__ u3,
                 float scale, float lm12, float lm3) {
    tri_pass(blockIdx.x, threadIdx.x >> 6, threadIdx.x & 63,
             C1, v1, u1, C2, v2, u2, C3, v3, u3, scale, lm12, lm3);
}

// plan+au+L_ot row body (row i of Cu & Ca)
__device__ __forceinline__ void plan_ot_row(int i, int lane,
                                            const u16* Cu, const u16* Ca,
                                            const float* uu, const float* vu,
                                            const float* ua, const float* va,
                                            u16* plan, float* au, float* slotOt, float scale) {
    const s8v* ru = (const s8v*)(Cu + (size_t)i * 4096);
    const s8v* ra = (const s8v*)(Ca + (size_t)i * 4096);
    s8v* p8 = (s8v*)(plan + (size_t)i * 4096);
    const float4* vu4 = (const float4*)vu;
    const float4* va4 = (const float4*)va;
    float uui = uu[i], uai = ua[i];
    float sa = 0.f, ot = 0.f;
    for (int c = lane; c < 512; c += 64) {
        s8v u8 = ru[c], a8 = ra[c], pb;
        float4 u0 = vu4[c * 2], u1 = vu4[c * 2 + 1];
        float4 a0 = va4[c * 2], a1 = va4[c * 2 + 1];
        float uv[8] = {u0.x, u0.y, u0.z, u0.w, u1.x, u1.y, u1.z, u1.w};
        float av[8] = {a0.x, a0.y, a0.z, a0.w, a1.x, a1.y, a1.z, a1.w};
#pragma unroll
        for (int k = 0; k < 8; ++k) {
            float lpu = b2f((u16)u8[k]) * scale + uui + uv[k];
            float p = __expf(lpu);
            sa += p;
            pb[k] = (short)f2b(p);
            float lpa = b2f((u16)a8[k]) * scale + uai + av[k];
            ot += __expf(lpa) * (lpa - lpu);
        }
        p8[c] = pb;
    }
    sa = wave_sum(sa);
    if (lane == 0) au[i] = sa;
    ot = wave_sum(ot);
    block_atomic4(ot, slotOt);
}

__device__ __forceinline__ void pairs_rowsum(int r, int lane,
                                             const u16* cosp, const float* up, const float* vp,
                                             float* ap, float scale) {
    const s8v* r8 = (const s8v*)(cosp + (size_t)r * 2048);
    const float4* vp4 = (const float4*)vp;
    float ui = up[r], s = 0.f;
    for (int c = lane; c < 256; c += 64) {
        s8v v8 = r8[c];
        float4 v0 = vp4[c * 2], v1 = vp4[c * 2 + 1];
        float vv[8] = {v0.x, v0.y, v0.z, v0.w, v1.x, v1.y, v1.z, v1.w};
#pragma unroll
        for (int k = 0; k < 8; ++k)
            s += __expf(b2f((u16)v8[k]) * scale + ui + vv[k]);
    }
    s = wave_sum(s);
    if (lane == 0) ap[r] = s;
}

__device__ __forceinline__ void sail_row(int row, int lane,
                                         const u16* cosb, float temp, float* slot) {
    const s8v* r8 = (const s8v*)(cosb + (size_t)row * 2048);
    float local = 0.f;
    for (int c = lane; c < 256; c += 64) {
        s8v v8 = r8[c];
#pragma unroll
        for (int k = 0; k < 8; ++k) {
            int j = c * 8 + k;
            float cv = b2f((u16)v8[k]);
            float wgt = cv * ((j == row) ? temp : -temp);
            local -= fminf(wgt, 0.f) - log1pf(__expf(-fabsf(wgt)));
        }
    }
    local = wave_sum(local);
    block_atomic4(local, slot);
}

__device__ __forceinline__ void marg_body(const float* sv, int n, float target, float* slot) {
    int t = threadIdx.x;
    float s = 0.f;
    for (int i = t; i < n; i += 256) { float d = sv[i] - target; s += d * d; }
    __shared__ float buf[256];
    float tot = block_sum(s, buf);
    if (t == 0) atomicAdd(slot, tot);
}

__device__ __forceinline__ void diag_body(const u16* cosb, const float* up, const float* vp,
                                          float scale, float* slotExp, float* slotImp) {
    int t = threadIdx.x;
    float e = 0.f, im = 0.f;
    float logn = logf(2048.f);
    for (int i = t; i < 2048; i += 256) {
        float c = b2f(cosb[(size_t)i * 2048 + i]);
        e  += (1.f - c) * 0.5f;
        im += scale * c + up[i] + vp[i] + logn;
    }
    __shared__ float buf[256];
    float te = block_sum(e, buf);
    float ti = block_sum(im, buf);
    if (t == 0) { atomicAdd(slotExp, te); atomicAdd(slotImp, ti); }
}

// ---------------- cooperative fused sinkhorn + plan + tails ----------------
struct SK {
    const u16 *Cu, *CuT, *Ca, *CaT, *cosp, *cospT;
    float *uu, *vu, *ua, *va, *up, *vp;
    u16* plan;
    float *au, *ap;
    float* slots;        // 0 marg, 1 sail, 2 exp, 3 imp, 4 ot
    float scale, lm12, lm3;
};

__global__ __launch_bounds__(256, 5)
void sink_coop(SK a) {
    cg::grid_group g = cg::this_grid();
    const int wv = threadIdx.x >> 6;
    const int lane = threadIdx.x & 63;
    for (int it = 0; it < 10; ++it) {
        for (int s = blockIdx.x; s < 2560; s += gridDim.x)
            tri_pass(s, wv, lane, a.Cu, a.vu, a.uu, a.Ca, a.va, a.ua,
                     a.cosp, a.vp, a.up, a.scale, a.lm12, a.lm3);
        g.sync();
        for (int s = blockIdx.x; s < 2560; s += gridDim.x)
            tri_pass(s, wv, lane, a.CuT, a.uu, a.vu, a.CaT, a.ua, a.va,
                     a.cospT, a.up, a.vp, a.scale, a.lm12, a.lm3);
        g.sync();
    }
    // plan + au + L_ot + pairs rowsums (1536 slots)
    for (int s = blockIdx.x; s < 1536; s += gridDim.x) {
        if (s < 1024)
            plan_ot_row(s * 4 + wv, lane, a.Cu, a.Ca, a.uu, a.vu, a.ua, a.va,
                        a.plan, a.au, a.slots + 4, a.scale);
        else
            pairs_rowsum((s - 1024) * 4 + wv, lane, a.cosp, a.up, a.vp, a.ap, a.scale);
    }
    g.sync();
    // tails: sail (512 slots), marg ap (512), marg au (513), diag (514)
    for (int s = blockIdx.x; s < 515; s += gridDim.x) {
        if (s < 512)       sail_row(s * 4 + wv, lane, a.cosp, 10.f, a.slots + 1);
        else if (s == 512) marg_body(a.ap, 2048, 1.f / 2048.f, a.slots + 0);
        else if (s == 513) marg_body(a.au, 4096, 1.f / 4096.f, a.slots + 0);
        else               diag_body(a.cosp, a.up, a.vp, a.scale, a.slots + 2, a.slots + 3);
    }
}

// ---------------- fallback dispatch kernels ----------------
__global__ __launch_bounds__(256)
void plan_ot(const u16* __restrict__ Cu, const u16* __restrict__ Ca,
             const u16* __restrict__ cosp,
             const float* __restrict__ uu, const float* __restrict__ vu,
             const float* __restrict__ ua, const float* __restrict__ va,
             const float* __restrict__ up, const float* __restrict__ vp,
             u16* __restrict__ plan,
             float* __restrict__ au, float* __restrict__ ap,
             float* __restrict__ slotOt, float scale) {
    int wv = threadIdx.x >> 6, lane = threadIdx.x & 63;
    if (blockIdx.x < 1024)
        plan_ot_row(blockIdx.x * 4 + wv, lane, Cu, Ca, uu, vu, ua, va, plan, au, slotOt, scale);
    else
        pairs_rowsum((blockIdx.x - 1024) * 4 + wv, lane, cosp, up, vp, ap, scale);
}

__global__ __launch_bounds__(256)
void tail_fused(const u16* __restrict__ cosp,
                const float* __restrict__ ap, const float* __restrict__ au,
                const float* __restrict__ up, const float* __restrict__ vp,
                float scale, float* __restrict__ slots) {
    int s = blockIdx.x;
    int wv = threadIdx.x >> 6, lane = threadIdx.x & 63;
    if (s < 512)       sail_row(s * 4 + wv, lane, cosp, 10.f, slots + 1);
    else if (s == 512) marg_body(ap, 2048, 1.f / 2048.f, slots + 0);
    else if (s == 513) marg_body(au, 4096, 1.f / 4096.f, slots + 0);
    else               diag_body(cosp, up, vp, scale, slots + 2, slots + 3);
}

// reduce split-K slices (2 each): T1T bf16 + ||W1||^2 + ||(1/4096)W2||^2
__global__ __launch_bounds__(256)
void gw_reduce(const float* __restrict__ T1S, u16* __restrict__ T1T,
               const float* __restrict__ W1S, const float* __restrict__ W2S,
               float* __restrict__ s8, float* __restrict__ s9) {
    int b = blockIdx.x, t = threadIdx.x;
    if (b < 512) {
        const int n = 512 * 4096;
        for (int i = b * 256 + t; i < n; i += 512 * 256)
            T1T[i] = f2b(T1S[i] + T1S[i + n]);
    } else if (b < 548) {
        const int n = 768 * 768;
        float local = 0.f;
        for (int i = (b - 512) * 256 + t; i < n; i += 36 * 256) {
            float v = W1S[i] + W1S[i + n];
            local += v * v;
        }
        __shared__ float buf[256];
        float tot = block_sum(local, buf);
        if (t == 0) atomicAdd(s8, tot);
    } else {
        const int n = 512 * 512;
        const float sc = 1.f / 4096.f;
        float local = 0.f;
        for (int i = (b - 548) * 256 + t; i < n; i += 16 * 256) {
            float v = (W2S[i] + W2S[i + n]) * sc;
            local += v * v;
        }
        __shared__ float buf[256];
        float tot = block_sum(local, buf);
        if (t == 0) atomicAdd(s9, tot);
    }
}

__global__ __launch_bounds__(256)
void dot_bb(const u16* __restrict__ A, const u16* __restrict__ B, int n,
            float* __restrict__ slot) {
    int t = threadIdx.x;
    float local = 0.f;
    for (int i = blockIdx.x * 256 + t; i < n; i += gridDim.x * 256)
        local += b2f(A[i]) * b2f(B[i]);
    __shared__ float buf[256];
    float tot = block_sum(local, buf);
    if (t == 0) atomicAdd(slot, tot);
}

__global__ __launch_bounds__(256)
void sumsq(const float* __restrict__ p, int n, float* __restrict__ slot) {
    int t = threadIdx.x;
    float local = 0.f;
    for (int i = blockIdx.x * 256 + t; i < n; i += gridDim.x * 256) {
        float v = p[i]; local += v * v;
    }
    __shared__ float buf[256];
    float tot = block_sum(local, buf);
    if (t == 0) atomicAdd(slot, tot);
}

// slots: 0 marg, 1 sail, 2 exp, 3 imp, 4 ot, 5 norm1, 6 norm2, 7 dot, 8 gw1, 9 gw2, 10 sandwich
__global__ void combine(const float* __restrict__ s, float* __restrict__ out) {
    if (threadIdx.x == 0 && blockIdx.x == 0) {
        float Np = 2048.f;
        float Nu2 = 4096.f * 4096.f;
        float total = s[0]
                    + s[1] / (Np * Np)
                    + s[2] / Np
                    - s[3] / Np
                    + s[4]
                    + (s[5] + s[6] - 2.f * s[7]) / Nu2
                    + s[8] + s[9] - 2.f * s[10];
        out[0] = total;
    }
}

// ------------------------------------------------------------------
extern "C" void kernel_launch(void* const* d_in, const int* in_sizes, int n_in,
                              void* d_out, int out_size, void* d_ws, size_t ws_size,
                              hipStream_t stream) {
    const float* fXp_in = (const float*)d_in[0];   // 2048 x 256
    const float* fYp_in = (const float*)d_in[1];   // 2048 x 256
    const float* X_in   = (const float*)d_in[2];   // 4096 x 768
    const float* Y_in   = (const float*)d_in[3];   // 4096 x 512
    const float* fX_in  = (const float*)d_in[4];   // 4096 x 256
    const float* fY_in  = (const float*)d_in[5];   // 4096 x 256
    const float* Xa_in  = (const float*)d_in[6];   // 4096 x 768
    const float* Ya_in  = (const float*)d_in[7];   // 4096 x 512
    float* out = (float*)d_out;

    char* w = (char*)d_ws;
    size_t off = 0;
    auto alloc = [&](size_t bytes) -> char* {
        char* p = w + off;
        off += (bytes + 255) & ~(size_t)255;
        return p;
    };

    const size_t N = 4096, Np = 2048, DX = 768, DY = 512, DF = 256;

    // ---- five shared 32 MB N x N slots (lifetime-scheduled) ----
    const size_t SLOT = N * N * 2;
    char* S1 = alloc(SLOT);
    char* S2 = alloc(SLOT);
    char* S3 = alloc(SLOT);
    char* S4 = alloc(SLOT);
    char* S5 = alloc(SLOT);

    // S1: Xa -> Cu -> T1T(bf16)
    u16* Xa   = (u16*)S1;
    u16* Cu   = (u16*)S1;
    u16* T1T  = (u16*)S1;
    // S2: Ya -> CuT -> XuT+YuT
    u16* Ya   = (u16*)S2;
    u16* CuT  = (u16*)S2;
    u16* XuT  = (u16*)S2;
    u16* YuT  = (u16*)(S2 + N * DX * 2);
    // S3: Ca -> XsT + W1S + W2S
    u16* Ca   = (u16*)S3;
    u16* XsT  = (u16*)S3;                          // 6 MB
    float* W1S = (float*)(S3 + 8 * 1024 * 1024);   // 2 x 2.36 MB
    float* W2S = (float*)(S3 + 20 * 1024 * 1024);  // 2 x 1.05 MB
    // S4: XaT+YaT -> XS -> XnT+YnT -> CaT -> T1S (2 slices x 8 MB)
    u16* XaT  = (u16*)S4;
    u16* YaT  = (u16*)(S4 + N * DX * 2);
    float* XS = (float*)S4;
    u16* XnT  = (u16*)S4;
    u16* YnT  = (u16*)(S4 + N * DX * 2);
    u16* CaT  = (u16*)S4;
    float* T1S= (float*)S4;
    // S5: YS -> Tb -> plan
    float* YS = (float*)S5;
    u16* Tb   = (u16*)S5;
    u16* plan = (u16*)S5;

    // ---- dedicated bf16 buffers ----
    u16* fXp  = (u16*)alloc(Np * DF * 2);
    u16* fYp  = (u16*)alloc(Np * DF * 2);
    u16* fXn  = (u16*)alloc(N * DF * 2);
    u16* fYn  = (u16*)alloc(N * DF * 2);
    u16* fXnT = (u16*)alloc(N * DF * 2);
    u16* fYnT = (u16*)alloc(N * DF * 2);
    u16* Xu   = (u16*)alloc(N * DX * 2);
    u16* Yu   = (u16*)alloc(N * DY * 2);
    u16* Xn   = (u16*)alloc(N * DX * 2);
    u16* Yn   = (u16*)alloc(N * DY * 2);
    u16* Sxx  = (u16*)alloc(DX * DX * 2);
    u16* Syy  = (u16*)alloc(DY * DY * 2);
    u16* SxyT = (u16*)alloc(DY * DX * 2);
    u16* Gx   = (u16*)alloc(DX * DX * 2);
    u16* Gy   = (u16*)alloc(DY * DY * 2);
    u16* Gfx  = (u16*)alloc(DF * DF * 2);
    u16* Gfy  = (u16*)alloc(DF * DF * 2);
    u16* A1b  = (u16*)alloc(DX * DF * 2);
    u16* B1Tb = (u16*)alloc(DY * DF * 2);
    u16* Hb   = (u16*)alloc(DX * DY * 2);
    u16* cosp = (u16*)alloc(Np * Np * 2);
    u16* cospT= (u16*)alloc(Np * Np * 2);
    float* ap = (float*)alloc(Np * 4);
    float* au = (float*)alloc(N * 4);

    // ---- zero zone (ONE memset): slots + potentials + fp32 atomic targets ----
    char* zero_begin = w + off;
    float* slots = (float*)alloc(64 * 4);
    float* up = (float*)alloc(Np * 4);
    float* vp = (float*)alloc(Np * 4);
    float* uu = (float*)alloc(N * 4);
    float* vu = (float*)alloc(N * 4);
    float* ua = (float*)alloc(N * 4);
    float* va = (float*)alloc(N * 4);
    float* SxxF  = (float*)alloc(DX * DX * 4);
    float* SyyF  = (float*)alloc(DY * DY * 4);
    float* SxyTF = (float*)alloc(DY * DX * 4);
    float* GxF   = (float*)alloc(DX * DX * 4);
    float* GyF   = (float*)alloc(DY * DY * 4);
    float* GfxF  = (float*)alloc(DF * DF * 4);
    float* GfyF  = (float*)alloc(DF * DF * 4);
    float* A1F   = (float*)alloc(DX * DF * 4);
    float* B1F   = (float*)alloc(DY * DF * 4);
    float* HbF   = (float*)alloc(DX * DY * 4);
    float* MF    = (float*)alloc(DX * DY * 4);
    size_t zero_bytes = (size_t)((w + off) - zero_begin);

    const float SCALE = 20.f;   // 1/eps
    const float LM12 = -logf(4096.f), LM3 = -logf(2048.f);

    hipMemsetAsync(zero_begin, 0, zero_bytes, stream);

    // ===== 1. all row-normalizations (one dispatch) =====
    {
        RNArgs a;
        a.d[0] = {Xa_in, Xa, 768, 4096};
        a.d[1] = {Ya_in, Ya, 512, 8192};
        a.d[2] = {fXp_in, fXp, 256, 10240};
        a.d[3] = {fYp_in, fYp, 256, 12288};
        a.d[4] = {fX_in, fXn, 256, 16384};
        a.d[5] = {fY_in, fYn, 256, 20480};
        a.d[6] = {X_in, Xu, 768, 24576};
        a.d[7] = {Y_in, Yu, 512, 28672};
        a.n = 8;
        rownorm_batch<<<7168, 256, 0, stream>>>(a);
    }

    // ===== 2. transposes A: XaT, YaT, fXnT, fYnT =====
    {
        TPArgs a;
        a.d[0] = {Xa, XaT, 4096, 768, 24, 3072, nullptr};
        a.d[1] = {Ya, YaT, 4096, 512, 16, 5120, nullptr};
        a.d[2] = {fXn, fXnT, 4096, 256, 8, 6144, nullptr};
        a.d[3] = {fYn, fYnT, 4096, 256, 8, 7168, nullptr};
        a.n = 4;
        transpose_batch<<<7168, 256, 0, stream>>>(a);
    }

    // ===== 3. batch1: anchor covariances (split-K8, atomic) + cast =====
    {
        BGNArgs g;
        g.d[0] = {XaT, XaT, SxxF, nullptr, nullptr, nullptr, 768, 768, 512, 4096, 0, 6, 36};
        g.d[1] = {YaT, YaT, SyyF, nullptr, nullptr, nullptr, 512, 512, 512, 4096, 0, 4, 52};
        g.d[2] = {YaT, XaT, SxyTF, nullptr, nullptr, nullptr, 512, 768, 512, 4096, 0, 6, 76};
        g.n = 3; g.alpha = 1.f / 4096.f;
        bgemmN<3><<<dim3(76, 8), 256, 0, stream>>>(g);
        cast_f2b<<<256, 256, 0, stream>>>(SxxF, Sxx, 768 * 768 + 512 * 512 + 512 * 768);
    }

    // ===== 4. Mahalanobis: XS/YS in one batched dispatch =====
    {
        BGNArgs g;
        g.d[0] = {Xu, Sxx, XS, nullptr, nullptr, nullptr, 4096, 768, 768, 768, 0, 6, 192};
        g.d[1] = {Yu, Syy, YS, nullptr, nullptr, nullptr, 4096, 512, 512, 512, 0, 4, 320};
        g.n = 2; g.alpha = 1.f;
        bgemmN<0><<<dim3(320, 1), 256, 0, stream>>>(g);
    }
    mahal_w<<<1024, 256, 0, stream>>>(Xu, XS, Xn, 4096, 768);
    mahal_w<<<1024, 256, 0, stream>>>(Yu, YS, Yn, 4096, 512);

    // ===== 5. transposes B: XnT, YnT (clobber XS in S4) =====
    {
        TPArgs a;
        a.d[0] = {Xn, XnT, 4096, 768, 24, 3072, nullptr};
        a.d[1] = {Yn, YnT, 4096, 512, 16, 5120, nullptr};
        a.n = 2;
        transpose_batch<<<5120, 256, 0, stream>>>(a);
    }

    // ===== 6. batch2: L_div gram matrices (split-K8, atomic) + cast =====
    {
        BGNArgs g;
        g.d[0] = {XnT, XnT, GxF, nullptr, nullptr, nullptr, 768, 768, 512, 4096, 0, 6, 36};
        g.d[1] = {YnT, YnT, GyF, nullptr, nullptr, nullptr, 512, 512, 512, 4096, 0, 4, 52};
        g.d[2] = {fXnT, fXnT, GfxF, nullptr, nullptr, nullptr, 256, 256, 512, 4096, 0, 2, 56};
        g.d[3] = {fYnT, fYnT, GfyF, nullptr, nullptr, nullptr, 256, 256, 512, 4096, 0, 2, 60};
        g.d[4] = {XnT, fXnT, A1F, nullptr, nullptr, nullptr, 768, 256, 512, 4096, 0, 2, 72};
        g.d[5] = {YnT, fYnT, B1F, nullptr, nullptr, nullptr, 512, 256, 512, 4096, 0, 2, 80};
        g.n = 6; g.alpha = 1.f;
        bgemmN<3><<<dim3(80, 8), 256, 0, stream>>>(g);
        cast_f2b<<<256, 256, 0, stream>>>(GxF, Gx,
            768 * 768 + 512 * 512 + 256 * 256 + 256 * 256 + 768 * 256 + 512 * 256);
    }

    // ===== 7. cost matrices Cu, cosp, Tb in ONE batched bf16 dispatch =====
    {
        BGNArgs g;
        g.d[0] = {fXn, fYn, nullptr, Cu, nullptr, nullptr, 4096, 4096, 256, 256, 0, 32, 1024};
        g.d[1] = {fXp, fYp, nullptr, cosp, nullptr, nullptr, 2048, 2048, 256, 256, 0, 16, 1280};
        g.d[2] = {Xn, SxyT, nullptr, Tb, nullptr, nullptr, 4096, 512, 768, 768, 0, 4, 1408};
        g.n = 3; g.alpha = 1.f;
        bgemmN<1><<<dim3(1408, 1), 256, 0, stream>>>(g);
    }
    gemm_bt<1><<<dim3(32, 32), 256, 0, stream>>>(Tb, Yn, nullptr, Ca, 4096, 4096, 512, 512, 1.f);

    // ===== 8. transposes C: CuT, cospT, CaT =====
    {
        TPArgs a;
        a.d[0] = {Cu, CuT, 4096, 4096, 128, 16384, nullptr};
        a.d[1] = {cosp, cospT, 2048, 2048, 64, 20480, nullptr};
        a.d[2] = {Ca, CaT, 4096, 4096, 128, 36864, nullptr};
        a.n = 3;
        transpose_batch<<<36864, 256, 0, stream>>>(a);
    }

    // ===== 9. L_div tail =====
    gemm_bt<3><<<dim3(4, 6, 4), 256, 0, stream>>>(Gx, SxyT, HbF, nullptr, 768, 512, 192, 768, 1.f);
    cast_f2b<<<256, 256, 0, stream>>>(HbF, Hb, 768 * 512);
    {
        BGNArgs g;
        g.d[0] = {Hb, Gy, nullptr, nullptr, SxyT, slots + 5, 768, 512, 128, 512, 768, 4, 24};
        g.d[1] = {A1b, B1Tb, nullptr, nullptr, SxyT, slots + 7, 768, 512, 64, 256, 768, 4, 48};
        g.n = 2; g.alpha = 1.f;
        bgemmN<2><<<dim3(48, 4), 256, 0, stream>>>(g);
    }
    dot_bb<<<64, 256, 0, stream>>>(Gfx, Gfy, 256 * 256, slots + 6);

    // ===== 10+11. fused sinkhorn + plan + tails: cooperative (fallback: dispatches) =====
    {
        SK sa;
        sa.Cu = Cu; sa.CuT = CuT; sa.Ca = Ca; sa.CaT = CaT; sa.cosp = cosp; sa.cospT = cospT;
        sa.uu = uu; sa.vu = vu; sa.ua = ua; sa.va = va; sa.up = up; sa.vp = vp;
        sa.plan = plan; sa.au = au; sa.ap = ap; sa.slots = slots;
        sa.scale = SCALE; sa.lm12 = LM12; sa.lm3 = LM3;
        void* kargs[] = {&sa};
        hipError_t err = hipLaunchCooperativeKernel((const void*)sink_coop,
                                                    dim3(1280), dim3(256), kargs, 0, stream);
        if (err != hipSuccess) {
            // fallback: classic dispatch sequence (identical math)
            for (int it = 0; it < 10; ++it) {
                row_lse_tri<<<2560, 256, 0, stream>>>(Cu, vu, uu, Ca, va, ua, cosp, vp, up, SCALE, LM12, LM3);
                row_lse_tri<<<2560, 256, 0, stream>>>(CuT, uu, vu, CaT, ua, va, cospT, up, vp, SCALE, LM12, LM3);
            }
            plan_ot<<<1536, 256, 0, stream>>>(Cu, Ca, cosp, uu, vu, ua, va, up, vp,
                                              plan, au, ap, slots + 4, SCALE);
            tail_fused<<<515, 256, 0, stream>>>(cosp, ap, au, up, vp, SCALE, slots);
        }
    }

    // ===== 12. GW via low-rank identities (slice split-K2, no atomics) =====
    {
        TPArgs a;
        a.d[0] = {Xu, XuT, 4096, 768, 24, 3072, nullptr};
        a.d[1] = {Yu, YuT, 4096, 512, 16, 5120, nullptr};
        a.d[2] = {Xu, XsT, 4096, 768, 24, 8192, au};
        a.n = 3;
        transpose_batch<<<8192, 256, 0, stream>>>(a);
    }
    {
        BGNArgs g;
        g.d[0] = {YuT, plan, T1S, nullptr, nullptr, nullptr, 512, 4096, 2048, 4096, 0, 32, 128};
        g.d[1] = {XsT, XuT, W1S, nullptr, nullptr, nullptr, 768, 768, 2048, 4096, 0, 6, 164};
        g.d[2] = {YuT, YuT, W2S, nullptr, nullptr, nullptr, 512, 512, 2048, 4096, 0, 4, 180};
        g.n = 3; g.alpha = 1.f;
        bgemmN<4><<<dim3(180, 2), 256, 0, stream>>>(g);
    }
    gw_reduce<<<564, 256, 0, stream>>>(T1S, T1T, W1S, W2S, slots + 8, slots + 9);
    {
        BGNArgs g;
        g.d[0] = {XuT, T1T, MF, nullptr, nullptr, nullptr, 768, 512, 512, 4096, 0, 4, 24};
        g.n = 1; g.alpha = 1.f;
        bgemmN<3><<<dim3(24, 8), 256, 0, stream>>>(g);
    }
    sumsq<<<32, 256, 0, stream>>>(MF, 768 * 512, slots + 10);

    combine<<<1, 1, 0, stream>>>(slots, out);
}

// Round 10
// 852.035 us; speedup vs baseline: 4.3895x; 4.3895x over previous
//
#include <hip/hip_runtime.h>
#include <hip/hip_bf16.h>
#include <math.h>

using u16 = unsigned short;
using s8v = __attribute__((ext_vector_type(8))) short;   // 8 bf16 (4 VGPRs) - MFMA A/B frag
using s4v = __attribute__((ext_vector_type(4))) short;   // 4 bf16
using f4v = __attribute__((ext_vector_type(4))) float;   // MFMA C/D frag

__device__ __forceinline__ float b2f(u16 x) {
    unsigned int u = ((unsigned int)x) << 16;
    return __uint_as_float(u);
}
__device__ __forceinline__ u16 f2b(float f) {
    unsigned int x = __float_as_uint(f);
    unsigned int r = x + 0x7fffu + ((x >> 16) & 1u);   // RNE
    return (u16)(r >> 16);
}

// async global->LDS, 16B per lane; lds base wave-uniform (lane scatter = lane*16)
__device__ __forceinline__ void a16(u16* lds, const u16* g) {
    __builtin_amdgcn_global_load_lds((__attribute__((address_space(1))) void*)g,
                                     (__attribute__((address_space(3))) void*)lds,
                                     16, 0, 0);
}

// ---------------- reductions ----------------
__device__ __forceinline__ float block_sum(float v, float* buf) {
    int t = threadIdx.x;
    buf[t] = v; __syncthreads();
    for (int s = 128; s > 0; s >>= 1) {
        if (t < s) buf[t] += buf[t + s];
        __syncthreads();
    }
    float r = buf[0];
    __syncthreads();
    return r;
}

__device__ __forceinline__ float wave_sum(float v) {
#pragma unroll
    for (int off = 32; off; off >>= 1) v += __shfl_xor(v, off, 64);
    return v;
}

__device__ __forceinline__ void block_atomic4(float wval, float* slot) {
    __shared__ float wb[4];
    int lane = threadIdx.x & 63, wv = threadIdx.x >> 6;
    if (lane == 0) wb[wv] = wval;
    __syncthreads();
    if (threadIdx.x == 0) atomicAdd(slot, wb[0] + wb[1] + wb[2] + wb[3]);
    __syncthreads();
}

// ---------------- GEMM core ----------------
#define TBM 128
#define TBN 128
#define TBK 32

// single-problem GEMM. EPI: 1 -> bf16 C, 3 -> atomicAdd fp32 C (split-K via blockIdx.z)
template<int EPI>
__global__ __launch_bounds__(256)
void gemm_bt(const u16* __restrict__ A, const u16* __restrict__ B,
             float* __restrict__ Cf, u16* __restrict__ Cb,
             int M, int N, int K, int ld, float alpha)
{
    __shared__ __align__(16) u16 As[TBM * TBK];
    __shared__ __align__(16) u16 Bs[TBN * TBK];

    const int tid  = threadIdx.x;
    const int lane = tid & 63;
    const int wave = tid >> 6;
    const int wm   = (wave >> 1) * 64;
    const int wn   = (wave & 1) * 64;
    const int l16  = lane & 15;
    const int q4   = lane >> 4;
    const size_t row0 = (size_t)blockIdx.y * TBM;
    const size_t col0 = (size_t)blockIdx.x * TBN;
    const int kOff = blockIdx.z * K;

    f4v acc[4][4];
#pragma unroll
    for (int mt = 0; mt < 4; ++mt)
#pragma unroll
        for (int nt = 0; nt < 4; ++nt)
#pragma unroll
            for (int r = 0; r < 4; ++r)
                acc[mt][nt][r] = 0.f;

    const int ar0 = wave * 32 + (lane >> 2);
    const int ar1 = ar0 + 16;
    const int akk = (lane & 3) * 8;
    const u16* gA0 = A + (row0 + ar0) * ld + kOff + akk;
    const u16* gA1 = A + (row0 + ar1) * ld + kOff + akk;
    const u16* gB0 = B + (col0 + ar0) * ld + kOff + akk;
    const u16* gB1 = B + (col0 + ar1) * ld + kOff + akk;
    u16* lA0 = As + wave * 1024;
    u16* lA1 = As + wave * 1024 + 512;
    u16* lB0 = Bs + wave * 1024;
    u16* lB1 = Bs + wave * 1024 + 512;

    for (int k0 = 0; k0 < K; k0 += TBK) {
        __syncthreads();
        a16(lA0, gA0 + k0);
        a16(lA1, gA1 + k0);
        a16(lB0, gB0 + k0);
        a16(lB1, gB1 + k0);
        __syncthreads();

        s8v af[4], bfr[4];
#pragma unroll
        for (int mt = 0; mt < 4; ++mt)
            af[mt] = *(const s8v*)(As + (wm + mt * 16 + l16) * TBK + q4 * 8);
#pragma unroll
        for (int nt = 0; nt < 4; ++nt)
            bfr[nt] = *(const s8v*)(Bs + (wn + nt * 16 + l16) * TBK + q4 * 8);
#pragma unroll
        for (int mt = 0; mt < 4; ++mt)
#pragma unroll
            for (int nt = 0; nt < 4; ++nt)
                acc[mt][nt] = __builtin_amdgcn_mfma_f32_16x16x32_bf16(af[mt], bfr[nt], acc[mt][nt], 0, 0, 0);
    }

#pragma unroll
    for (int mt = 0; mt < 4; ++mt)
#pragma unroll
        for (int nt = 0; nt < 4; ++nt)
#pragma unroll
            for (int r = 0; r < 4; ++r) {
                size_t row = row0 + wm + mt * 16 + q4 * 4 + r;
                size_t col = col0 + wn + nt * 16 + l16;
                float v = acc[mt][nt][r] * alpha;
                if (EPI == 1) Cb[row * (size_t)N + col] = f2b(v);
                else          atomicAdd(&Cf[row * (size_t)N + col], v);
            }
}

// ---------------- generalized batched GEMM ----------------
// EPI: 0 -> store fp32 (z=1), 1 -> store bf16 (z=1),
//      2 -> dot epilogue: atomicAdd(slot, sum(C .* W^T)) with W[col*WL+row],
//      3 -> atomicAdd fp32 C (split-K),
//      4 -> store fp32 to per-slice buffer Cf + z*M*N (split-K, no atomics)
struct BGN {
    const u16* A; const u16* B;
    float* Cf; u16* Cb;
    const u16* W; float* slot;
    int M, N, Kc, ld, WL, tN, tEnd;
};
struct BGNArgs { BGN d[6]; int n; float alpha; };

template<int EPI>
__global__ __launch_bounds__(256)
void bgemmN(BGNArgs g)
{
    __shared__ __align__(16) u16 As[TBM * TBK];
    __shared__ __align__(16) u16 Bs[TBN * TBK];

    int bi = 0;
    while (bi < g.n - 1 && (int)blockIdx.x >= g.d[bi].tEnd) ++bi;
    const BGN& d = g.d[bi];
    const int tStart = bi ? g.d[bi - 1].tEnd : 0;
    const int local = blockIdx.x - tStart;
    const int tm = local / d.tN;
    const int tn = local - tm * d.tN;

    const int tid  = threadIdx.x;
    const int lane = tid & 63;
    const int wave = tid >> 6;
    const int wm   = (wave >> 1) * 64;
    const int wn   = (wave & 1) * 64;
    const int l16  = lane & 15;
    const int q4   = lane >> 4;
    const size_t row0 = (size_t)tm * TBM;
    const size_t col0 = (size_t)tn * TBN;
    const int kOff = blockIdx.y * d.Kc;
    const int ld = d.ld;

    f4v acc[4][4];
#pragma unroll
    for (int mt = 0; mt < 4; ++mt)
#pragma unroll
        for (int nt = 0; nt < 4; ++nt)
#pragma unroll
            for (int r = 0; r < 4; ++r)
                acc[mt][nt][r] = 0.f;

    const int ar0 = wave * 32 + (lane >> 2);
    const int ar1 = ar0 + 16;
    const int akk = (lane & 3) * 8;
    const u16* gA0 = d.A + (row0 + ar0) * ld + kOff + akk;
    const u16* gA1 = d.A + (row0 + ar1) * ld + kOff + akk;
    const u16* gB0 = d.B + (col0 + ar0) * ld + kOff + akk;
    const u16* gB1 = d.B + (col0 + ar1) * ld + kOff + akk;
    u16* lA0 = As + wave * 1024;
    u16* lA1 = As + wave * 1024 + 512;
    u16* lB0 = Bs + wave * 1024;
    u16* lB1 = Bs + wave * 1024 + 512;

    for (int k0 = 0; k0 < d.Kc; k0 += TBK) {
        __syncthreads();
        a16(lA0, gA0 + k0);
        a16(lA1, gA1 + k0);
        a16(lB0, gB0 + k0);
        a16(lB1, gB1 + k0);
        __syncthreads();

        s8v af[4], bfr[4];
#pragma unroll
        for (int mt = 0; mt < 4; ++mt)
            af[mt] = *(const s8v*)(As + (wm + mt * 16 + l16) * TBK + q4 * 8);
#pragma unroll
        for (int nt = 0; nt < 4; ++nt)
            bfr[nt] = *(const s8v*)(Bs + (wn + nt * 16 + l16) * TBK + q4 * 8);
#pragma unroll
        for (int mt = 0; mt < 4; ++mt)
#pragma unroll
            for (int nt = 0; nt < 4; ++nt)
                acc[mt][nt] = __builtin_amdgcn_mfma_f32_16x16x32_bf16(af[mt], bfr[nt], acc[mt][nt], 0, 0, 0);
    }

    if (EPI == 2) {
        float local2 = 0.f;
#pragma unroll
        for (int mt = 0; mt < 4; ++mt)
#pragma unroll
            for (int nt = 0; nt < 4; ++nt)
#pragma unroll
                for (int r = 0; r < 4; ++r) {
                    size_t row = row0 + wm + mt * 16 + q4 * 4 + r;
                    size_t col = col0 + wn + nt * 16 + l16;
                    local2 += acc[mt][nt][r] * b2f(d.W[col * (size_t)d.WL + row]);
                }
        __shared__ float red[256];
        float tot = block_sum(local2 * g.alpha, red);
        if (tid == 0) atomicAdd(d.slot, tot);
    } else {
        float* Cs = (EPI == 4) ? d.Cf + (size_t)blockIdx.y * d.M * d.N : d.Cf;
#pragma unroll
        for (int mt = 0; mt < 4; ++mt)
#pragma unroll
            for (int nt = 0; nt < 4; ++nt)
#pragma unroll
                for (int r = 0; r < 4; ++r) {
                    size_t row = row0 + wm + mt * 16 + q4 * 4 + r;
                    size_t col = col0 + wn + nt * 16 + l16;
                    float v = acc[mt][nt][r] * g.alpha;
                    if (EPI == 0)      d.Cf[row * (size_t)d.N + col] = v;
                    else if (EPI == 1) d.Cb[row * (size_t)d.N + col] = f2b(v);
                    else if (EPI == 4) Cs[row * (size_t)d.N + col] = v;
                    else               atomicAdd(&d.Cf[row * (size_t)d.N + col], v);
                }
    }
}

// ---------------- batched rownorm ----------------
struct RN { const float* in; u16* out; int C; int rEnd; };
struct RNArgs { RN d[8]; int n; };

__global__ __launch_bounds__(256)
void rownorm_batch(RNArgs a) {
    int gw = (blockIdx.x * 256 + threadIdx.x) >> 6;
    int lane = threadIdx.x & 63;
    int i = 0;
    while (i < a.n - 1 && gw >= a.d[i].rEnd) ++i;
    if (gw >= a.d[i].rEnd) return;
    int row = gw - (i ? a.d[i - 1].rEnd : 0);
    int C = a.d[i].C;
    const float4* r4 = (const float4*)(a.d[i].in + (size_t)row * C);
    int nv = C >> 2;
    float ss = 0.f;
    for (int c = lane; c < nv; c += 64) {
        float4 v = r4[c];
        ss += v.x * v.x + v.y * v.y + v.z * v.z + v.w * v.w;
    }
    ss = wave_sum(ss);
    float inv = 1.f / fmaxf(sqrtf(ss), 1e-8f);
    s4v* o4 = (s4v*)(a.d[i].out + (size_t)row * C);
    for (int c = lane; c < nv; c += 64) {
        float4 v = r4[c];
        s4v o;
        o[0] = (short)f2b(v.x * inv); o[1] = (short)f2b(v.y * inv);
        o[2] = (short)f2b(v.z * inv); o[3] = (short)f2b(v.w * inv);
        o4[c] = o;
    }
}

__global__ __launch_bounds__(256)
void mahal_w(const u16* __restrict__ Xh, const float* __restrict__ XS,
             u16* __restrict__ out, int nrows, int C) {
    int row = (blockIdx.x * 256 + threadIdx.x) >> 6;
    int lane = threadIdx.x & 63;
    if (row >= nrows) return;
    const s4v* x4 = (const s4v*)(Xh + (size_t)row * C);
    const float4* s4 = (const float4*)(XS + (size_t)row * C);
    int nv = C >> 2;
    float s = 0.f;
    for (int c = lane; c < nv; c += 64) {
        s4v x = x4[c]; float4 v = s4[c];
        s += b2f((u16)x[0]) * v.x + b2f((u16)x[1]) * v.y
           + b2f((u16)x[2]) * v.z + b2f((u16)x[3]) * v.w;
    }
    s = wave_sum(s);
    float inv = 1.f / fmaxf(sqrtf(fmaxf(s, 0.f)), 1e-8f);
    s4v* o4 = (s4v*)(out + (size_t)row * C);
    for (int c = lane; c < nv; c += 64) {
        s4v x = x4[c], o;
#pragma unroll
        for (int k = 0; k < 4; ++k) o[k] = (short)f2b(b2f((u16)x[k]) * inv);
        o4[c] = o;
    }
}

// ---------------- batched 32x32 transpose (optional per-input-row scale) ------
struct TP { const u16* in; u16* out; int R, C, tC, tEnd; const float* s; };
struct TPArgs { TP d[6]; int n; };

__global__ __launch_bounds__(256)
void transpose_batch(TPArgs a) {
    __shared__ u16 tile[32][33];
    int t = blockIdx.x;
    int i = 0;
    while (i < a.n - 1 && t >= a.d[i].tEnd) ++i;
    int local = t - (i ? a.d[i - 1].tEnd : 0);
    const TP& d = a.d[i];
    int ty = local / d.tC, tx = local - ty * d.tC;
    int bx = tx * 32, by = ty * 32;
    int lx = threadIdx.x & 31;
    int lyy = threadIdx.x >> 5;
    for (int r = lyy; r < 32; r += 8)
        tile[r][lx] = d.in[(size_t)(by + r) * d.C + bx + lx];
    __syncthreads();
    for (int r = lyy; r < 32; r += 8) {
        u16 val = tile[lx][r];
        if (d.s) val = f2b(b2f(val) * d.s[by + lx]);
        d.out[(size_t)(bx + r) * d.R + by + lx] = val;
    }
}

__global__ __launch_bounds__(256)
void cast_f2b(const float* __restrict__ in, u16* __restrict__ out, int n) {
    for (int i = blockIdx.x * 256 + threadIdx.x; i < n; i += gridDim.x * 256)
        out[i] = f2b(in[i]);
}

// ---------------- sinkhorn row pass (no-max sum-exp; logits bounded) ----------
__device__ __forceinline__ float row_sumexp(const u16* __restrict__ rowp,
                                            const float* __restrict__ vin,
                                            int ny, float scale, int lane) {
    const s8v* r8 = (const s8v*)rowp;
    const float4* v4 = (const float4*)vin;
    int nv = ny >> 3;
    float s = 0.f;
    for (int c = lane; c < nv; c += 64) {
        s8v v8 = r8[c];
        float4 va = v4[c * 2], vb = v4[c * 2 + 1];
        s += __expf(b2f((u16)v8[0]) * scale + va.x);
        s += __expf(b2f((u16)v8[1]) * scale + va.y);
        s += __expf(b2f((u16)v8[2]) * scale + va.z);
        s += __expf(b2f((u16)v8[3]) * scale + va.w);
        s += __expf(b2f((u16)v8[4]) * scale + vb.x);
        s += __expf(b2f((u16)v8[5]) * scale + vb.y);
        s += __expf(b2f((u16)v8[6]) * scale + vb.z);
        s += __expf(b2f((u16)v8[7]) * scale + vb.w);
    }
    return wave_sum(s);
}

// one half-iteration pass over 3 problems; slot = virtual row group [0,2560)
__device__ __forceinline__ void tri_pass(int s, int wv, int lane,
                                         const u16* C1, const float* v1, float* u1,
                                         const u16* C2, const float* v2, float* u2,
                                         const u16* C3, const float* v3, float* u3,
                                         float scale, float lm12, float lm3) {
    int gw = s * 4 + wv;
    if (gw < 4096) {
        float t = row_sumexp(C1 + (size_t)gw * 4096, v1, 4096, scale, lane);
        if (lane == 0) u1[gw] = lm12 - __logf(t);
    } else if (gw < 8192) {
        int r = gw - 4096;
        float t = row_sumexp(C2 + (size_t)r * 4096, v2, 4096, scale, lane);
        if (lane == 0) u2[r] = lm12 - __logf(t);
    } else if (gw < 10240) {
        int r = gw - 8192;
        float t = row_sumexp(C3 + (size_t)r * 2048, v3, 2048, scale, lane);
        if (lane == 0) u3[r] = lm3 - __logf(t);
    }
}

__global__ __launch_bounds__(256)
void row_lse_tri(const u16* __restrict__ C1, const float* __restrict__ v1, float* __restrict__ u1,
                 const u16* __restrict__ C2, const float* __restrict__ v2, float* __restrict__ u2,
                 const u16* __restrict__ C3, const float* __restrict__ v3, float* __restrict__ u3,
                 float scale, float lm12, float lm3) {
    tri_pass(blockIdx.x, threadIdx.x >> 6, threadIdx.x & 63,
             C1, v1, u1, C2, v2, u2, C3, v3, u3, scale, lm12, lm3);
}

// plan+au+L_ot row body (row i of Cu & Ca)
__device__ __forceinline__ void plan_ot_row(int i, int lane,
                                            const u16* Cu, const u16* Ca,
                                            const float* uu, const float* vu,
                                            const float* ua, const float* va,
                                            u16* plan, float* au, float* slotOt, float scale) {
    const s8v* ru = (const s8v*)(Cu + (size_t)i * 4096);
    const s8v* ra = (const s8v*)(Ca + (size_t)i * 4096);
    s8v* p8 = (s8v*)(plan + (size_t)i * 4096);
    const float4* vu4 = (const float4*)vu;
    const float4* va4 = (const float4*)va;
    float uui = uu[i], uai = ua[i];
    float sa = 0.f, ot = 0.f;
    for (int c = lane; c < 512; c += 64) {
        s8v u8 = ru[c], a8 = ra[c], pb;
        float4 u0 = vu4[c * 2], u1 = vu4[c * 2 + 1];
        float4 a0 = va4[c * 2], a1 = va4[c * 2 + 1];
        float uv[8] = {u0.x, u0.y, u0.z, u0.w, u1.x, u1.y, u1.z, u1.w};
        float av[8] = {a0.x, a0.y, a0.z, a0.w, a1.x, a1.y, a1.z, a1.w};
#pragma unroll
        for (int k = 0; k < 8; ++k) {
            float lpu = b2f((u16)u8[k]) * scale + uui + uv[k];
            float p = __expf(lpu);
            sa += p;
            pb[k] = (short)f2b(p);
            float lpa = b2f((u16)a8[k]) * scale + uai + av[k];
            ot += __expf(lpa) * (lpa - lpu);
        }
        p8[c] = pb;
    }
    sa = wave_sum(sa);
    if (lane == 0) au[i] = sa;
    ot = wave_sum(ot);
    block_atomic4(ot, slotOt);
}

__device__ __forceinline__ void pairs_rowsum(int r, int lane,
                                             const u16* cosp, const float* up, const float* vp,
                                             float* ap, float scale) {
    const s8v* r8 = (const s8v*)(cosp + (size_t)r * 2048);
    const float4* vp4 = (const float4*)vp;
    float ui = up[r], s = 0.f;
    for (int c = lane; c < 256; c += 64) {
        s8v v8 = r8[c];
        float4 v0 = vp4[c * 2], v1 = vp4[c * 2 + 1];
        float vv[8] = {v0.x, v0.y, v0.z, v0.w, v1.x, v1.y, v1.z, v1.w};
#pragma unroll
        for (int k = 0; k < 8; ++k)
            s += __expf(b2f((u16)v8[k]) * scale + ui + vv[k]);
    }
    s = wave_sum(s);
    if (lane == 0) ap[r] = s;
}

__device__ __forceinline__ void sail_row(int row, int lane,
                                         const u16* cosb, float temp, float* slot) {
    const s8v* r8 = (const s8v*)(cosb + (size_t)row * 2048);
    float local = 0.f;
    for (int c = lane; c < 256; c += 64) {
        s8v v8 = r8[c];
#pragma unroll
        for (int k = 0; k < 8; ++k) {
            int j = c * 8 + k;
            float cv = b2f((u16)v8[k]);
            float wgt = cv * ((j == row) ? temp : -temp);
            local -= fminf(wgt, 0.f) - log1pf(__expf(-fabsf(wgt)));
        }
    }
    local = wave_sum(local);
    block_atomic4(local, slot);
}

__device__ __forceinline__ void marg_body(const float* sv, int n, float target, float* slot) {
    int t = threadIdx.x;
    float s = 0.f;
    for (int i = t; i < n; i += 256) { float d = sv[i] - target; s += d * d; }
    __shared__ float buf[256];
    float tot = block_sum(s, buf);
    if (t == 0) atomicAdd(slot, tot);
}

__device__ __forceinline__ void diag_body(const u16* cosb, const float* up, const float* vp,
                                          float scale, float* slotExp, float* slotImp) {
    int t = threadIdx.x;
    float e = 0.f, im = 0.f;
    float logn = logf(2048.f);
    for (int i = t; i < 2048; i += 256) {
        float c = b2f(cosb[(size_t)i * 2048 + i]);
        e  += (1.f - c) * 0.5f;
        im += scale * c + up[i] + vp[i] + logn;
    }
    __shared__ float buf[256];
    float te = block_sum(e, buf);
    float ti = block_sum(im, buf);
    if (t == 0) { atomicAdd(slotExp, te); atomicAdd(slotImp, ti); }
}

__global__ __launch_bounds__(256)
void plan_ot(const u16* __restrict__ Cu, const u16* __restrict__ Ca,
             const u16* __restrict__ cosp,
             const float* __restrict__ uu, const float* __restrict__ vu,
             const float* __restrict__ ua, const float* __restrict__ va,
             const float* __restrict__ up, const float* __restrict__ vp,
             u16* __restrict__ plan,
             float* __restrict__ au, float* __restrict__ ap,
             float* __restrict__ slotOt, float scale) {
    int wv = threadIdx.x >> 6, lane = threadIdx.x & 63;
    if (blockIdx.x < 1024)
        plan_ot_row(blockIdx.x * 4 + wv, lane, Cu, Ca, uu, vu, ua, va, plan, au, slotOt, scale);
    else
        pairs_rowsum((blockIdx.x - 1024) * 4 + wv, lane, cosp, up, vp, ap, scale);
}

__global__ __launch_bounds__(256)
void tail_fused(const u16* __restrict__ cosp,
                const float* __restrict__ ap, const float* __restrict__ au,
                const float* __restrict__ up, const float* __restrict__ vp,
                float scale, float* __restrict__ slots) {
    int s = blockIdx.x;
    int wv = threadIdx.x >> 6, lane = threadIdx.x & 63;
    if (s < 512)       sail_row(s * 4 + wv, lane, cosp, 10.f, slots + 1);
    else if (s == 512) marg_body(ap, 2048, 1.f / 2048.f, slots + 0);
    else if (s == 513) marg_body(au, 4096, 1.f / 4096.f, slots + 0);
    else               diag_body(cosp, up, vp, scale, slots + 2, slots + 3);
}

// reduce split-K slices (2 each): T1T bf16 + ||W1||^2 + ||(1/4096)W2||^2
__global__ __launch_bounds__(256)
void gw_reduce(const float* __restrict__ T1S, u16* __restrict__ T1T,
               const float* __restrict__ W1S, const float* __restrict__ W2S,
               float* __restrict__ s8, float* __restrict__ s9) {
    int b = blockIdx.x, t = threadIdx.x;
    if (b < 512) {
        const int n = 512 * 4096;
        for (int i = b * 256 + t; i < n; i += 512 * 256)
            T1T[i] = f2b(T1S[i] + T1S[i + n]);
    } else if (b < 548) {
        const int n = 768 * 768;
        float local = 0.f;
        for (int i = (b - 512) * 256 + t; i < n; i += 36 * 256) {
            float v = W1S[i] + W1S[i + n];
            local += v * v;
        }
        __shared__ float buf[256];
        float tot = block_sum(local, buf);
        if (t == 0) atomicAdd(s8, tot);
    } else {
        const int n = 512 * 512;
        const float sc = 1.f / 4096.f;
        float local = 0.f;
        for (int i = (b - 548) * 256 + t; i < n; i += 16 * 256) {
            float v = (W2S[i] + W2S[i + n]) * sc;
            local += v * v;
        }
        __shared__ float buf[256];
        float tot = block_sum(local, buf);
        if (t == 0) atomicAdd(s9, tot);
    }
}

__global__ __launch_bounds__(256)
void dot_bb(const u16* __restrict__ A, const u16* __restrict__ B, int n,
            float* __restrict__ slot) {
    int t = threadIdx.x;
    float local = 0.f;
    for (int i = blockIdx.x * 256 + t; i < n; i += gridDim.x * 256)
        local += b2f(A[i]) * b2f(B[i]);
    __shared__ float buf[256];
    float tot = block_sum(local, buf);
    if (t == 0) atomicAdd(slot, tot);
}

__global__ __launch_bounds__(256)
void sumsq(const float* __restrict__ p, int n, float* __restrict__ slot) {
    int t = threadIdx.x;
    float local = 0.f;
    for (int i = blockIdx.x * 256 + t; i < n; i += gridDim.x * 256) {
        float v = p[i]; local += v * v;
    }
    __shared__ float buf[256];
    float tot = block_sum(local, buf);
    if (t == 0) atomicAdd(slot, tot);
}

// slots: 0 marg, 1 sail, 2 exp, 3 imp, 4 ot, 5 norm1, 6 norm2, 7 dot, 8 gw1, 9 gw2, 10 sandwich
__global__ void combine(const float* __restrict__ s, float* __restrict__ out) {
    if (threadIdx.x == 0 && blockIdx.x == 0) {
        float Np = 2048.f;
        float Nu2 = 4096.f * 4096.f;
        float total = s[0]
                    + s[1] / (Np * Np)
                    + s[2] / Np
                    - s[3] / Np
                    + s[4]
                    + (s[5] + s[6] - 2.f * s[7]) / Nu2
                    + s[8] + s[9] - 2.f * s[10];
        out[0] = total;
    }
}

// ------------------------------------------------------------------
extern "C" void kernel_launch(void* const* d_in, const int* in_sizes, int n_in,
                              void* d_out, int out_size, void* d_ws, size_t ws_size,
                              hipStream_t stream) {
    const float* fXp_in = (const float*)d_in[0];   // 2048 x 256
    const float* fYp_in = (const float*)d_in[1];   // 2048 x 256
    const float* X_in   = (const float*)d_in[2];   // 4096 x 768
    const float* Y_in   = (const float*)d_in[3];   // 4096 x 512
    const float* fX_in  = (const float*)d_in[4];   // 4096 x 256
    const float* fY_in  = (const float*)d_in[5];   // 4096 x 256
    const float* Xa_in  = (const float*)d_in[6];   // 4096 x 768
    const float* Ya_in  = (const float*)d_in[7];   // 4096 x 512
    float* out = (float*)d_out;

    char* w = (char*)d_ws;
    size_t off = 0;
    auto alloc = [&](size_t bytes) -> char* {
        char* p = w + off;
        off += (bytes + 255) & ~(size_t)255;
        return p;
    };

    const size_t N = 4096, Np = 2048, DX = 768, DY = 512, DF = 256;

    // ---- five shared 32 MB N x N slots (lifetime-scheduled) ----
    const size_t SLOT = N * N * 2;
    char* S1 = alloc(SLOT);
    char* S2 = alloc(SLOT);
    char* S3 = alloc(SLOT);
    char* S4 = alloc(SLOT);
    char* S5 = alloc(SLOT);

    // S1: Xa -> Cu -> T1T(bf16)
    u16* Xa   = (u16*)S1;
    u16* Cu   = (u16*)S1;
    u16* T1T  = (u16*)S1;
    // S2: Ya -> CuT -> XuT+YuT
    u16* Ya   = (u16*)S2;
    u16* CuT  = (u16*)S2;
    u16* XuT  = (u16*)S2;
    u16* YuT  = (u16*)(S2 + N * DX * 2);
    // S3: Ca -> XsT + W1S + W2S
    u16* Ca   = (u16*)S3;
    u16* XsT  = (u16*)S3;                          // 6 MB
    float* W1S = (float*)(S3 + 8 * 1024 * 1024);   // 2 x 2.36 MB
    float* W2S = (float*)(S3 + 20 * 1024 * 1024);  // 2 x 1.05 MB
    // S4: XaT+YaT -> XS -> XnT+YnT -> CaT -> T1S (2 slices x 8 MB)
    u16* XaT  = (u16*)S4;
    u16* YaT  = (u16*)(S4 + N * DX * 2);
    float* XS = (float*)S4;
    u16* XnT  = (u16*)S4;
    u16* YnT  = (u16*)(S4 + N * DX * 2);
    u16* CaT  = (u16*)S4;
    float* T1S= (float*)S4;
    // S5: YS -> Tb -> plan
    float* YS = (float*)S5;
    u16* Tb   = (u16*)S5;
    u16* plan = (u16*)S5;

    // ---- dedicated bf16 buffers ----
    u16* fXp  = (u16*)alloc(Np * DF * 2);
    u16* fYp  = (u16*)alloc(Np * DF * 2);
    u16* fXn  = (u16*)alloc(N * DF * 2);
    u16* fYn  = (u16*)alloc(N * DF * 2);
    u16* fXnT = (u16*)alloc(N * DF * 2);
    u16* fYnT = (u16*)alloc(N * DF * 2);
    u16* Xu   = (u16*)alloc(N * DX * 2);
    u16* Yu   = (u16*)alloc(N * DY * 2);
    u16* Xn   = (u16*)alloc(N * DX * 2);
    u16* Yn   = (u16*)alloc(N * DY * 2);
    u16* Sxx  = (u16*)alloc(DX * DX * 2);
    u16* Syy  = (u16*)alloc(DY * DY * 2);
    u16* SxyT = (u16*)alloc(DY * DX * 2);
    u16* Gx   = (u16*)alloc(DX * DX * 2);
    u16* Gy   = (u16*)alloc(DY * DY * 2);
    u16* Gfx  = (u16*)alloc(DF * DF * 2);
    u16* Gfy  = (u16*)alloc(DF * DF * 2);
    u16* A1b  = (u16*)alloc(DX * DF * 2);
    u16* B1Tb = (u16*)alloc(DY * DF * 2);
    u16* Hb   = (u16*)alloc(DX * DY * 2);
    u16* cosp = (u16*)alloc(Np * Np * 2);
    u16* cospT= (u16*)alloc(Np * Np * 2);
    float* ap = (float*)alloc(Np * 4);
    float* au = (float*)alloc(N * 4);

    // ---- zero zone (ONE memset): slots + potentials + fp32 atomic targets ----
    char* zero_begin = w + off;
    float* slots = (float*)alloc(64 * 4);
    float* up = (float*)alloc(Np * 4);
    float* vp = (float*)alloc(Np * 4);
    float* uu = (float*)alloc(N * 4);
    float* vu = (float*)alloc(N * 4);
    float* ua = (float*)alloc(N * 4);
    float* va = (float*)alloc(N * 4);
    float* SxxF  = (float*)alloc(DX * DX * 4);
    float* SyyF  = (float*)alloc(DY * DY * 4);
    float* SxyTF = (float*)alloc(DY * DX * 4);
    float* GxF   = (float*)alloc(DX * DX * 4);
    float* GyF   = (float*)alloc(DY * DY * 4);
    float* GfxF  = (float*)alloc(DF * DF * 4);
    float* GfyF  = (float*)alloc(DF * DF * 4);
    float* A1F   = (float*)alloc(DX * DF * 4);
    float* B1F   = (float*)alloc(DY * DF * 4);
    float* HbF   = (float*)alloc(DX * DY * 4);
    float* MF    = (float*)alloc(DX * DY * 4);
    size_t zero_bytes = (size_t)((w + off) - zero_begin);

    const float SCALE = 20.f;   // 1/eps
    const float LM12 = -logf(4096.f), LM3 = -logf(2048.f);

    hipMemsetAsync(zero_begin, 0, zero_bytes, stream);

    // ===== 1. all row-normalizations (one dispatch) =====
    {
        RNArgs a;
        a.d[0] = {Xa_in, Xa, 768, 4096};
        a.d[1] = {Ya_in, Ya, 512, 8192};
        a.d[2] = {fXp_in, fXp, 256, 10240};
        a.d[3] = {fYp_in, fYp, 256, 12288};
        a.d[4] = {fX_in, fXn, 256, 16384};
        a.d[5] = {fY_in, fYn, 256, 20480};
        a.d[6] = {X_in, Xu, 768, 24576};
        a.d[7] = {Y_in, Yu, 512, 28672};
        a.n = 8;
        rownorm_batch<<<7168, 256, 0, stream>>>(a);
    }

    // ===== 2. transposes A: XaT, YaT, fXnT, fYnT =====
    {
        TPArgs a;
        a.d[0] = {Xa, XaT, 4096, 768, 24, 3072, nullptr};
        a.d[1] = {Ya, YaT, 4096, 512, 16, 5120, nullptr};
        a.d[2] = {fXn, fXnT, 4096, 256, 8, 6144, nullptr};
        a.d[3] = {fYn, fYnT, 4096, 256, 8, 7168, nullptr};
        a.n = 4;
        transpose_batch<<<7168, 256, 0, stream>>>(a);
    }

    // ===== 3. batch1: anchor covariances (split-K8, atomic) + cast =====
    {
        BGNArgs g;
        g.d[0] = {XaT, XaT, SxxF, nullptr, nullptr, nullptr, 768, 768, 512, 4096, 0, 6, 36};
        g.d[1] = {YaT, YaT, SyyF, nullptr, nullptr, nullptr, 512, 512, 512, 4096, 0, 4, 52};
        g.d[2] = {YaT, XaT, SxyTF, nullptr, nullptr, nullptr, 512, 768, 512, 4096, 0, 6, 76};
        g.n = 3; g.alpha = 1.f / 4096.f;
        bgemmN<3><<<dim3(76, 8), 256, 0, stream>>>(g);
        cast_f2b<<<256, 256, 0, stream>>>(SxxF, Sxx, 768 * 768 + 512 * 512 + 512 * 768);
    }

    // ===== 4. Mahalanobis: XS/YS in one batched dispatch =====
    {
        BGNArgs g;
        g.d[0] = {Xu, Sxx, XS, nullptr, nullptr, nullptr, 4096, 768, 768, 768, 0, 6, 192};
        g.d[1] = {Yu, Syy, YS, nullptr, nullptr, nullptr, 4096, 512, 512, 512, 0, 4, 320};
        g.n = 2; g.alpha = 1.f;
        bgemmN<0><<<dim3(320, 1), 256, 0, stream>>>(g);
    }
    mahal_w<<<1024, 256, 0, stream>>>(Xu, XS, Xn, 4096, 768);
    mahal_w<<<1024, 256, 0, stream>>>(Yu, YS, Yn, 4096, 512);

    // ===== 5. transposes B: XnT, YnT (clobber XS in S4) =====
    {
        TPArgs a;
        a.d[0] = {Xn, XnT, 4096, 768, 24, 3072, nullptr};
        a.d[1] = {Yn, YnT, 4096, 512, 16, 5120, nullptr};
        a.n = 2;
        transpose_batch<<<5120, 256, 0, stream>>>(a);
    }

    // ===== 6. batch2: L_div gram matrices (split-K8, atomic) + cast =====
    {
        BGNArgs g;
        g.d[0] = {XnT, XnT, GxF, nullptr, nullptr, nullptr, 768, 768, 512, 4096, 0, 6, 36};
        g.d[1] = {YnT, YnT, GyF, nullptr, nullptr, nullptr, 512, 512, 512, 4096, 0, 4, 52};
        g.d[2] = {fXnT, fXnT, GfxF, nullptr, nullptr, nullptr, 256, 256, 512, 4096, 0, 2, 56};
        g.d[3] = {fYnT, fYnT, GfyF, nullptr, nullptr, nullptr, 256, 256, 512, 4096, 0, 2, 60};
        g.d[4] = {XnT, fXnT, A1F, nullptr, nullptr, nullptr, 768, 256, 512, 4096, 0, 2, 72};
        g.d[5] = {YnT, fYnT, B1F, nullptr, nullptr, nullptr, 512, 256, 512, 4096, 0, 2, 80};
        g.n = 6; g.alpha = 1.f;
        bgemmN<3><<<dim3(80, 8), 256, 0, stream>>>(g);
        cast_f2b<<<256, 256, 0, stream>>>(GxF, Gx,
            768 * 768 + 512 * 512 + 256 * 256 + 256 * 256 + 768 * 256 + 512 * 256);
    }

    // ===== 7. cost matrices Cu, cosp, Tb in ONE batched bf16 dispatch =====
    {
        BGNArgs g;
        g.d[0] = {fXn, fYn, nullptr, Cu, nullptr, nullptr, 4096, 4096, 256, 256, 0, 32, 1024};
        g.d[1] = {fXp, fYp, nullptr, cosp, nullptr, nullptr, 2048, 2048, 256, 256, 0, 16, 1280};
        g.d[2] = {Xn, SxyT, nullptr, Tb, nullptr, nullptr, 4096, 512, 768, 768, 0, 4, 1408};
        g.n = 3; g.alpha = 1.f;
        bgemmN<1><<<dim3(1408, 1), 256, 0, stream>>>(g);
    }
    gemm_bt<1><<<dim3(32, 32), 256, 0, stream>>>(Tb, Yn, nullptr, Ca, 4096, 4096, 512, 512, 1.f);

    // ===== 8. transposes C: CuT, cospT, CaT =====
    {
        TPArgs a;
        a.d[0] = {Cu, CuT, 4096, 4096, 128, 16384, nullptr};
        a.d[1] = {cosp, cospT, 2048, 2048, 64, 20480, nullptr};
        a.d[2] = {Ca, CaT, 4096, 4096, 128, 36864, nullptr};
        a.n = 3;
        transpose_batch<<<36864, 256, 0, stream>>>(a);
    }

    // ===== 9. L_div tail =====
    gemm_bt<3><<<dim3(4, 6, 4), 256, 0, stream>>>(Gx, SxyT, HbF, nullptr, 768, 512, 192, 768, 1.f);
    cast_f2b<<<256, 256, 0, stream>>>(HbF, Hb, 768 * 512);
    {
        BGNArgs g;
        g.d[0] = {Hb, Gy, nullptr, nullptr, SxyT, slots + 5, 768, 512, 128, 512, 768, 4, 24};
        g.d[1] = {A1b, B1Tb, nullptr, nullptr, SxyT, slots + 7, 768, 512, 64, 256, 768, 4, 48};
        g.n = 2; g.alpha = 1.f;
        bgemmN<2><<<dim3(48, 4), 256, 0, stream>>>(g);
    }
    dot_bb<<<64, 256, 0, stream>>>(Gfx, Gfy, 256 * 256, slots + 6);

    // ===== 10. triple-fused sinkhorn, 10 iters (dispatch path — coop grid.sync
    //           measured 13x slower on 8-XCD MI355X; see round-9 post-mortem) =====
    for (int it = 0; it < 10; ++it) {
        row_lse_tri<<<2560, 256, 0, stream>>>(Cu, vu, uu, Ca, va, ua, cosp, vp, up, SCALE, LM12, LM3);
        row_lse_tri<<<2560, 256, 0, stream>>>(CuT, uu, vu, CaT, ua, va, cospT, up, vp, SCALE, LM12, LM3);
    }

    // ===== 11. fused plan + au + L_ot + pairs rowsums, then fused tails =====
    plan_ot<<<1536, 256, 0, stream>>>(Cu, Ca, cosp, uu, vu, ua, va, up, vp,
                                      plan, au, ap, slots + 4, SCALE);
    tail_fused<<<515, 256, 0, stream>>>(cosp, ap, au, up, vp, SCALE, slots);

    // ===== 12. GW via low-rank identities (slice split-K2, no atomics) =====
    {
        TPArgs a;
        a.d[0] = {Xu, XuT, 4096, 768, 24, 3072, nullptr};
        a.d[1] = {Yu, YuT, 4096, 512, 16, 5120, nullptr};
        a.d[2] = {Xu, XsT, 4096, 768, 24, 8192, au};
        a.n = 3;
        transpose_batch<<<8192, 256, 0, stream>>>(a);
    }
    {
        BGNArgs g;
        g.d[0] = {YuT, plan, T1S, nullptr, nullptr, nullptr, 512, 4096, 2048, 4096, 0, 32, 128};
        g.d[1] = {XsT, XuT, W1S, nullptr, nullptr, nullptr, 768, 768, 2048, 4096, 0, 6, 164};
        g.d[2] = {YuT, YuT, W2S, nullptr, nullptr, nullptr, 512, 512, 2048, 4096, 0, 4, 180};
        g.n = 3; g.alpha = 1.f;
        bgemmN<4><<<dim3(180, 2), 256, 0, stream>>>(g);
    }
    gw_reduce<<<564, 256, 0, stream>>>(T1S, T1T, W1S, W2S, slots + 8, slots + 9);
    {
        BGNArgs g;
        g.d[0] = {XuT, T1T, MF, nullptr, nullptr, nullptr, 768, 512, 512, 4096, 0, 4, 24};
        g.n = 1; g.alpha = 1.f;
        bgemmN<3><<<dim3(24, 8), 256, 0, stream>>>(g);
    }
    sumsq<<<32, 256, 0, stream>>>(MF, 768 * 512, slots + 10);

    combine<<<1, 1, 0, stream>>>(slots, out);
}

// Round 11
// 840.290 us; speedup vs baseline: 4.4509x; 1.0140x over previous
//
#include <hip/hip_runtime.h>
#include <hip/hip_bf16.h>
#include <math.h>

using u16 = unsigned short;
using s8v = __attribute__((ext_vector_type(8))) short;   // 8 bf16 (4 VGPRs) - MFMA A/B frag
using s4v = __attribute__((ext_vector_type(4))) short;   // 4 bf16
using f4v = __attribute__((ext_vector_type(4))) float;   // MFMA C/D frag

__device__ __forceinline__ float b2f(u16 x) {
    unsigned int u = ((unsigned int)x) << 16;
    return __uint_as_float(u);
}
__device__ __forceinline__ u16 f2b(float f) {
    unsigned int x = __float_as_uint(f);
    unsigned int r = x + 0x7fffu + ((x >> 16) & 1u);   // RNE
    return (u16)(r >> 16);
}

// async global->LDS, 16B per lane; lds base wave-uniform (lane scatter = lane*16)
__device__ __forceinline__ void a16(u16* lds, const u16* g) {
    __builtin_amdgcn_global_load_lds((__attribute__((address_space(1))) void*)g,
                                     (__attribute__((address_space(3))) void*)lds,
                                     16, 0, 0);
}

// ---------------- reductions ----------------
__device__ __forceinline__ float block_sum(float v, float* buf) {
    int t = threadIdx.x;
    buf[t] = v; __syncthreads();
    for (int s = 128; s > 0; s >>= 1) {
        if (t < s) buf[t] += buf[t + s];
        __syncthreads();
    }
    float r = buf[0];
    __syncthreads();
    return r;
}

__device__ __forceinline__ float wave_sum(float v) {
#pragma unroll
    for (int off = 32; off; off >>= 1) v += __shfl_xor(v, off, 64);
    return v;
}

__device__ __forceinline__ void block_atomic4(float wval, float* slot) {
    __shared__ float wb[4];
    int lane = threadIdx.x & 63, wv = threadIdx.x >> 6;
    if (lane == 0) wb[wv] = wval;
    __syncthreads();
    if (threadIdx.x == 0) atomicAdd(slot, wb[0] + wb[1] + wb[2] + wb[3]);
    __syncthreads();
}

// ---------------- GEMM core ----------------
#define TBM 128
#define TBN 128
#define TBK 32

// single-problem GEMM. EPI: 1 -> bf16 C, 3 -> atomicAdd fp32 C (split-K via blockIdx.z)
template<int EPI>
__global__ __launch_bounds__(256)
void gemm_bt(const u16* __restrict__ A, const u16* __restrict__ B,
             float* __restrict__ Cf, u16* __restrict__ Cb,
             int M, int N, int K, int ld, float alpha)
{
    __shared__ __align__(16) u16 As[TBM * TBK];
    __shared__ __align__(16) u16 Bs[TBN * TBK];

    const int tid  = threadIdx.x;
    const int lane = tid & 63;
    const int wave = tid >> 6;
    const int wm   = (wave >> 1) * 64;
    const int wn   = (wave & 1) * 64;
    const int l16  = lane & 15;
    const int q4   = lane >> 4;
    const size_t row0 = (size_t)blockIdx.y * TBM;
    const size_t col0 = (size_t)blockIdx.x * TBN;
    const int kOff = blockIdx.z * K;

    f4v acc[4][4];
#pragma unroll
    for (int mt = 0; mt < 4; ++mt)
#pragma unroll
        for (int nt = 0; nt < 4; ++nt)
#pragma unroll
            for (int r = 0; r < 4; ++r)
                acc[mt][nt][r] = 0.f;

    const int ar0 = wave * 32 + (lane >> 2);
    const int ar1 = ar0 + 16;
    const int akk = (lane & 3) * 8;
    const u16* gA0 = A + (row0 + ar0) * ld + kOff + akk;
    const u16* gA1 = A + (row0 + ar1) * ld + kOff + akk;
    const u16* gB0 = B + (col0 + ar0) * ld + kOff + akk;
    const u16* gB1 = B + (col0 + ar1) * ld + kOff + akk;
    u16* lA0 = As + wave * 1024;
    u16* lA1 = As + wave * 1024 + 512;
    u16* lB0 = Bs + wave * 1024;
    u16* lB1 = Bs + wave * 1024 + 512;

    for (int k0 = 0; k0 < K; k0 += TBK) {
        __syncthreads();
        a16(lA0, gA0 + k0);
        a16(lA1, gA1 + k0);
        a16(lB0, gB0 + k0);
        a16(lB1, gB1 + k0);
        __syncthreads();

        s8v af[4], bfr[4];
#pragma unroll
        for (int mt = 0; mt < 4; ++mt)
            af[mt] = *(const s8v*)(As + (wm + mt * 16 + l16) * TBK + q4 * 8);
#pragma unroll
        for (int nt = 0; nt < 4; ++nt)
            bfr[nt] = *(const s8v*)(Bs + (wn + nt * 16 + l16) * TBK + q4 * 8);
#pragma unroll
        for (int mt = 0; mt < 4; ++mt)
#pragma unroll
            for (int nt = 0; nt < 4; ++nt)
                acc[mt][nt] = __builtin_amdgcn_mfma_f32_16x16x32_bf16(af[mt], bfr[nt], acc[mt][nt], 0, 0, 0);
    }

#pragma unroll
    for (int mt = 0; mt < 4; ++mt)
#pragma unroll
        for (int nt = 0; nt < 4; ++nt)
#pragma unroll
            for (int r = 0; r < 4; ++r) {
                size_t row = row0 + wm + mt * 16 + q4 * 4 + r;
                size_t col = col0 + wn + nt * 16 + l16;
                float v = acc[mt][nt][r] * alpha;
                if (EPI == 1) Cb[row * (size_t)N + col] = f2b(v);
                else          atomicAdd(&Cf[row * (size_t)N + col], v);
            }
}

// ---------------- generalized batched GEMM ----------------
// EPI: 0 -> store fp32 (z=1), 1 -> store bf16 (z=1),
//      2 -> dot epilogue: atomicAdd(slot, sum(C .* W^T)) with W[col*WL+row],
//      3 -> atomicAdd fp32 C (split-K),
//      4 -> store fp32 to per-slice buffer Cf + z*M*N (split-K, no atomics)
struct BGN {
    const u16* A; const u16* B;
    float* Cf; u16* Cb;
    const u16* W; float* slot;
    int M, N, Kc, ld, WL, tN, tEnd;
};
struct BGNArgs { BGN d[6]; int n; float alpha; };

template<int EPI>
__global__ __launch_bounds__(256)
void bgemmN(BGNArgs g)
{
    __shared__ __align__(16) u16 As[TBM * TBK];
    __shared__ __align__(16) u16 Bs[TBN * TBK];

    int bi = 0;
    while (bi < g.n - 1 && (int)blockIdx.x >= g.d[bi].tEnd) ++bi;
    const BGN& d = g.d[bi];
    const int tStart = bi ? g.d[bi - 1].tEnd : 0;
    const int local = blockIdx.x - tStart;
    const int tm = local / d.tN;
    const int tn = local - tm * d.tN;

    const int tid  = threadIdx.x;
    const int lane = tid & 63;
    const int wave = tid >> 6;
    const int wm   = (wave >> 1) * 64;
    const int wn   = (wave & 1) * 64;
    const int l16  = lane & 15;
    const int q4   = lane >> 4;
    const size_t row0 = (size_t)tm * TBM;
    const size_t col0 = (size_t)tn * TBN;
    const int kOff = blockIdx.y * d.Kc;
    const int ld = d.ld;

    f4v acc[4][4];
#pragma unroll
    for (int mt = 0; mt < 4; ++mt)
#pragma unroll
        for (int nt = 0; nt < 4; ++nt)
#pragma unroll
            for (int r = 0; r < 4; ++r)
                acc[mt][nt][r] = 0.f;

    const int ar0 = wave * 32 + (lane >> 2);
    const int ar1 = ar0 + 16;
    const int akk = (lane & 3) * 8;
    const u16* gA0 = d.A + (row0 + ar0) * ld + kOff + akk;
    const u16* gA1 = d.A + (row0 + ar1) * ld + kOff + akk;
    const u16* gB0 = d.B + (col0 + ar0) * ld + kOff + akk;
    const u16* gB1 = d.B + (col0 + ar1) * ld + kOff + akk;
    u16* lA0 = As + wave * 1024;
    u16* lA1 = As + wave * 1024 + 512;
    u16* lB0 = Bs + wave * 1024;
    u16* lB1 = Bs + wave * 1024 + 512;

    for (int k0 = 0; k0 < d.Kc; k0 += TBK) {
        __syncthreads();
        a16(lA0, gA0 + k0);
        a16(lA1, gA1 + k0);
        a16(lB0, gB0 + k0);
        a16(lB1, gB1 + k0);
        __syncthreads();

        s8v af[4], bfr[4];
#pragma unroll
        for (int mt = 0; mt < 4; ++mt)
            af[mt] = *(const s8v*)(As + (wm + mt * 16 + l16) * TBK + q4 * 8);
#pragma unroll
        for (int nt = 0; nt < 4; ++nt)
            bfr[nt] = *(const s8v*)(Bs + (wn + nt * 16 + l16) * TBK + q4 * 8);
#pragma unroll
        for (int mt = 0; mt < 4; ++mt)
#pragma unroll
            for (int nt = 0; nt < 4; ++nt)
                acc[mt][nt] = __builtin_amdgcn_mfma_f32_16x16x32_bf16(af[mt], bfr[nt], acc[mt][nt], 0, 0, 0);
    }

    if (EPI == 2) {
        float local2 = 0.f;
#pragma unroll
        for (int mt = 0; mt < 4; ++mt)
#pragma unroll
            for (int nt = 0; nt < 4; ++nt)
#pragma unroll
                for (int r = 0; r < 4; ++r) {
                    size_t row = row0 + wm + mt * 16 + q4 * 4 + r;
                    size_t col = col0 + wn + nt * 16 + l16;
                    local2 += acc[mt][nt][r] * b2f(d.W[col * (size_t)d.WL + row]);
                }
        __shared__ float red[256];
        float tot = block_sum(local2 * g.alpha, red);
        if (tid == 0) atomicAdd(d.slot, tot);
    } else {
        float* Cs = (EPI == 4) ? d.Cf + (size_t)blockIdx.y * d.M * d.N : d.Cf;
#pragma unroll
        for (int mt = 0; mt < 4; ++mt)
#pragma unroll
            for (int nt = 0; nt < 4; ++nt)
#pragma unroll
                for (int r = 0; r < 4; ++r) {
                    size_t row = row0 + wm + mt * 16 + q4 * 4 + r;
                    size_t col = col0 + wn + nt * 16 + l16;
                    float v = acc[mt][nt][r] * g.alpha;
                    if (EPI == 0)      d.Cf[row * (size_t)d.N + col] = v;
                    else if (EPI == 1) d.Cb[row * (size_t)d.N + col] = f2b(v);
                    else if (EPI == 4) Cs[row * (size_t)d.N + col] = v;
                    else               atomicAdd(&d.Cf[row * (size_t)d.N + col], v);
                }
    }
}

// ---------------- batched rownorm ----------------
struct RN { const float* in; u16* out; int C; int rEnd; };
struct RNArgs { RN d[8]; int n; };

__global__ __launch_bounds__(256)
void rownorm_batch(RNArgs a) {
    int gw = (blockIdx.x * 256 + threadIdx.x) >> 6;
    int lane = threadIdx.x & 63;
    int i = 0;
    while (i < a.n - 1 && gw >= a.d[i].rEnd) ++i;
    if (gw >= a.d[i].rEnd) return;
    int row = gw - (i ? a.d[i - 1].rEnd : 0);
    int C = a.d[i].C;
    const float4* r4 = (const float4*)(a.d[i].in + (size_t)row * C);
    int nv = C >> 2;
    float ss = 0.f;
    for (int c = lane; c < nv; c += 64) {
        float4 v = r4[c];
        ss += v.x * v.x + v.y * v.y + v.z * v.z + v.w * v.w;
    }
    ss = wave_sum(ss);
    float inv = 1.f / fmaxf(sqrtf(ss), 1e-8f);
    s4v* o4 = (s4v*)(a.d[i].out + (size_t)row * C);
    for (int c = lane; c < nv; c += 64) {
        float4 v = r4[c];
        s4v o;
        o[0] = (short)f2b(v.x * inv); o[1] = (short)f2b(v.y * inv);
        o[2] = (short)f2b(v.z * inv); o[3] = (short)f2b(v.w * inv);
        o4[c] = o;
    }
}

__global__ __launch_bounds__(256)
void mahal_w(const u16* __restrict__ Xh, const float* __restrict__ XS,
             u16* __restrict__ out, int nrows, int C) {
    int row = (blockIdx.x * 256 + threadIdx.x) >> 6;
    int lane = threadIdx.x & 63;
    if (row >= nrows) return;
    const s4v* x4 = (const s4v*)(Xh + (size_t)row * C);
    const float4* s4 = (const float4*)(XS + (size_t)row * C);
    int nv = C >> 2;
    float s = 0.f;
    for (int c = lane; c < nv; c += 64) {
        s4v x = x4[c]; float4 v = s4[c];
        s += b2f((u16)x[0]) * v.x + b2f((u16)x[1]) * v.y
           + b2f((u16)x[2]) * v.z + b2f((u16)x[3]) * v.w;
    }
    s = wave_sum(s);
    float inv = 1.f / fmaxf(sqrtf(fmaxf(s, 0.f)), 1e-8f);
    s4v* o4 = (s4v*)(out + (size_t)row * C);
    for (int c = lane; c < nv; c += 64) {
        s4v x = x4[c], o;
#pragma unroll
        for (int k = 0; k < 4; ++k) o[k] = (short)f2b(b2f((u16)x[k]) * inv);
        o4[c] = o;
    }
}

// ---------------- batched 32x32 transpose (optional per-input-row scale) ------
struct TP { const u16* in; u16* out; int R, C, tC, tEnd; const float* s; };
struct TPArgs { TP d[6]; int n; };

__global__ __launch_bounds__(256)
void transpose_batch(TPArgs a) {
    __shared__ u16 tile[32][33];
    int t = blockIdx.x;
    int i = 0;
    while (i < a.n - 1 && t >= a.d[i].tEnd) ++i;
    int local = t - (i ? a.d[i - 1].tEnd : 0);
    const TP& d = a.d[i];
    int ty = local / d.tC, tx = local - ty * d.tC;
    int bx = tx * 32, by = ty * 32;
    int lx = threadIdx.x & 31;
    int lyy = threadIdx.x >> 5;
    for (int r = lyy; r < 32; r += 8)
        tile[r][lx] = d.in[(size_t)(by + r) * d.C + bx + lx];
    __syncthreads();
    for (int r = lyy; r < 32; r += 8) {
        u16 val = tile[lx][r];
        if (d.s) val = f2b(b2f(val) * d.s[by + lx]);
        d.out[(size_t)(bx + r) * d.R + by + lx] = val;
    }
}

__global__ __launch_bounds__(256)
void cast_f2b(const float* __restrict__ in, u16* __restrict__ out, int n) {
    for (int i = blockIdx.x * 256 + threadIdx.x; i < n; i += gridDim.x * 256)
        out[i] = f2b(in[i]);
}

// ---------------- sinkhorn row pass (no-max sum-exp; logits bounded) ----------
__device__ __forceinline__ float row_sumexp(const u16* __restrict__ rowp,
                                            const float* __restrict__ vin,
                                            int ny, float scale, int lane) {
    const s8v* r8 = (const s8v*)rowp;
    const float4* v4 = (const float4*)vin;
    int nv = ny >> 3;
    float s = 0.f;
    for (int c = lane; c < nv; c += 64) {
        s8v v8 = r8[c];
        float4 va = v4[c * 2], vb = v4[c * 2 + 1];
        s += __expf(b2f((u16)v8[0]) * scale + va.x);
        s += __expf(b2f((u16)v8[1]) * scale + va.y);
        s += __expf(b2f((u16)v8[2]) * scale + va.z);
        s += __expf(b2f((u16)v8[3]) * scale + va.w);
        s += __expf(b2f((u16)v8[4]) * scale + vb.x);
        s += __expf(b2f((u16)v8[5]) * scale + vb.y);
        s += __expf(b2f((u16)v8[6]) * scale + vb.z);
        s += __expf(b2f((u16)v8[7]) * scale + vb.w);
    }
    return wave_sum(s);
}

// one half-iteration pass over 3 problems; slot = virtual row group [0,2560)
__device__ __forceinline__ void tri_pass(int s, int wv, int lane,
                                         const u16* C1, const float* v1, float* u1,
                                         const u16* C2, const float* v2, float* u2,
                                         const u16* C3, const float* v3, float* u3,
                                         float scale, float lm12, float lm3) {
    int gw = s * 4 + wv;
    if (gw < 4096) {
        float t = row_sumexp(C1 + (size_t)gw * 4096, v1, 4096, scale, lane);
        if (lane == 0) u1[gw] = lm12 - __logf(t);
    } else if (gw < 8192) {
        int r = gw - 4096;
        float t = row_sumexp(C2 + (size_t)r * 4096, v2, 4096, scale, lane);
        if (lane == 0) u2[r] = lm12 - __logf(t);
    } else if (gw < 10240) {
        int r = gw - 8192;
        float t = row_sumexp(C3 + (size_t)r * 2048, v3, 2048, scale, lane);
        if (lane == 0) u3[r] = lm3 - __logf(t);
    }
}

__global__ __launch_bounds__(256)
void row_lse_tri(const u16* __restrict__ C1, const float* __restrict__ v1, float* __restrict__ u1,
                 const u16* __restrict__ C2, const float* __restrict__ v2, float* __restrict__ u2,
                 const u16* __restrict__ C3, const float* __restrict__ v3, float* __restrict__ u3,
                 float scale, float lm12, float lm3) {
    tri_pass(blockIdx.x, threadIdx.x >> 6, threadIdx.x & 63,
             C1, v1, u1, C2, v2, u2, C3, v3, u3, scale, lm12, lm3);
}

// plan+au+L_ot row body (row i of Cu & Ca)
__device__ __forceinline__ void plan_ot_row(int i, int lane,
                                            const u16* Cu, const u16* Ca,
                                            const float* uu, const float* vu,
                                            const float* ua, const float* va,
                                            u16* plan, float* au, float* slotOt, float scale) {
    const s8v* ru = (const s8v*)(Cu + (size_t)i * 4096);
    const s8v* ra = (const s8v*)(Ca + (size_t)i * 4096);
    s8v* p8 = (s8v*)(plan + (size_t)i * 4096);
    const float4* vu4 = (const float4*)vu;
    const float4* va4 = (const float4*)va;
    float uui = uu[i], uai = ua[i];
    float sa = 0.f, ot = 0.f;
    for (int c = lane; c < 512; c += 64) {
        s8v u8 = ru[c], a8 = ra[c], pb;
        float4 u0 = vu4[c * 2], u1 = vu4[c * 2 + 1];
        float4 a0 = va4[c * 2], a1 = va4[c * 2 + 1];
        float uv[8] = {u0.x, u0.y, u0.z, u0.w, u1.x, u1.y, u1.z, u1.w};
        float av[8] = {a0.x, a0.y, a0.z, a0.w, a1.x, a1.y, a1.z, a1.w};
#pragma unroll
        for (int k = 0; k < 8; ++k) {
            float lpu = b2f((u16)u8[k]) * scale + uui + uv[k];
            float p = __expf(lpu);
            sa += p;
            pb[k] = (short)f2b(p);
            float lpa = b2f((u16)a8[k]) * scale + uai + av[k];
            ot += __expf(lpa) * (lpa - lpu);
        }
        p8[c] = pb;
    }
    sa = wave_sum(sa);
    if (lane == 0) au[i] = sa;
    ot = wave_sum(ot);
    block_atomic4(ot, slotOt);
}

__device__ __forceinline__ void pairs_rowsum(int r, int lane,
                                             const u16* cosp, const float* up, const float* vp,
                                             float* ap, float scale) {
    const s8v* r8 = (const s8v*)(cosp + (size_t)r * 2048);
    const float4* vp4 = (const float4*)vp;
    float ui = up[r], s = 0.f;
    for (int c = lane; c < 256; c += 64) {
        s8v v8 = r8[c];
        float4 v0 = vp4[c * 2], v1 = vp4[c * 2 + 1];
        float vv[8] = {v0.x, v0.y, v0.z, v0.w, v1.x, v1.y, v1.z, v1.w};
#pragma unroll
        for (int k = 0; k < 8; ++k)
            s += __expf(b2f((u16)v8[k]) * scale + ui + vv[k]);
    }
    s = wave_sum(s);
    if (lane == 0) ap[r] = s;
}

__device__ __forceinline__ void sail_row(int row, int lane,
                                         const u16* cosb, float temp, float* slot) {
    const s8v* r8 = (const s8v*)(cosb + (size_t)row * 2048);
    float local = 0.f;
    for (int c = lane; c < 256; c += 64) {
        s8v v8 = r8[c];
#pragma unroll
        for (int k = 0; k < 8; ++k) {
            int j = c * 8 + k;
            float cv = b2f((u16)v8[k]);
            float wgt = cv * ((j == row) ? temp : -temp);
            local -= fminf(wgt, 0.f) - log1pf(__expf(-fabsf(wgt)));
        }
    }
    local = wave_sum(local);
    block_atomic4(local, slot);
}

__device__ __forceinline__ void marg_body(const float* sv, int n, float target, float* slot) {
    int t = threadIdx.x;
    float s = 0.f;
    for (int i = t; i < n; i += 256) { float d = sv[i] - target; s += d * d; }
    __shared__ float buf[256];
    float tot = block_sum(s, buf);
    if (t == 0) atomicAdd(slot, tot);
}

__device__ __forceinline__ void diag_body(const u16* cosb, const float* up, const float* vp,
                                          float scale, float* slotExp, float* slotImp) {
    int t = threadIdx.x;
    float e = 0.f, im = 0.f;
    float logn = logf(2048.f);
    for (int i = t; i < 2048; i += 256) {
        float c = b2f(cosb[(size_t)i * 2048 + i]);
        e  += (1.f - c) * 0.5f;
        im += scale * c + up[i] + vp[i] + logn;
    }
    __shared__ float buf[256];
    float te = block_sum(e, buf);
    float ti = block_sum(im, buf);
    if (t == 0) { atomicAdd(slotExp, te); atomicAdd(slotImp, ti); }
}

__global__ __launch_bounds__(256)
void plan_ot(const u16* __restrict__ Cu, const u16* __restrict__ Ca,
             const u16* __restrict__ cosp,
             const float* __restrict__ uu, const float* __restrict__ vu,
             const float* __restrict__ ua, const float* __restrict__ va,
             const float* __restrict__ up, const float* __restrict__ vp,
             u16* __restrict__ plan,
             float* __restrict__ au, float* __restrict__ ap,
             float* __restrict__ slotOt, float scale) {
    int wv = threadIdx.x >> 6, lane = threadIdx.x & 63;
    if (blockIdx.x < 1024)
        plan_ot_row(blockIdx.x * 4 + wv, lane, Cu, Ca, uu, vu, ua, va, plan, au, slotOt, scale);
    else
        pairs_rowsum((blockIdx.x - 1024) * 4 + wv, lane, cosp, up, vp, ap, scale);
}

__global__ __launch_bounds__(256)
void tail_fused(const u16* __restrict__ cosp,
                const float* __restrict__ ap, const float* __restrict__ au,
                const float* __restrict__ up, const float* __restrict__ vp,
                float scale, float* __restrict__ slots) {
    int s = blockIdx.x;
    int wv = threadIdx.x >> 6, lane = threadIdx.x & 63;
    if (s < 512)       sail_row(s * 4 + wv, lane, cosp, 10.f, slots + 1);
    else if (s == 512) marg_body(ap, 2048, 1.f / 2048.f, slots + 0);
    else if (s == 513) marg_body(au, 4096, 1.f / 4096.f, slots + 0);
    else               diag_body(cosp, up, vp, scale, slots + 2, slots + 3);
}

// reduce split-K slices (4 each): T1T bf16 + ||W1||^2 + ||(1/4096)W2||^2
__global__ __launch_bounds__(256)
void gw_reduce(const float* __restrict__ T1S, u16* __restrict__ T1T,
               const float* __restrict__ W1S, const float* __restrict__ W2S,
               float* __restrict__ s8, float* __restrict__ s9) {
    int b = blockIdx.x, t = threadIdx.x;
    if (b < 512) {
        const int n = 512 * 4096, st = n;
        for (int i = b * 256 + t; i < n; i += 512 * 256)
            T1T[i] = f2b(T1S[i] + T1S[i + st] + T1S[i + 2 * st] + T1S[i + 3 * st]);
    } else if (b < 548) {
        const int n = 768 * 768, st = n;
        float local = 0.f;
        for (int i = (b - 512) * 256 + t; i < n; i += 36 * 256) {
            float v = W1S[i] + W1S[i + st] + W1S[i + 2 * st] + W1S[i + 3 * st];
            local += v * v;
        }
        __shared__ float buf[256];
        float tot = block_sum(local, buf);
        if (t == 0) atomicAdd(s8, tot);
    } else {
        const int n = 512 * 512, st = n;
        const float sc = 1.f / 4096.f;
        float local = 0.f;
        for (int i = (b - 548) * 256 + t; i < n; i += 16 * 256) {
            float v = (W2S[i] + W2S[i + st] + W2S[i + 2 * st] + W2S[i + 3 * st]) * sc;
            local += v * v;
        }
        __shared__ float buf[256];
        float tot = block_sum(local, buf);
        if (t == 0) atomicAdd(s9, tot);
    }
}

__global__ __launch_bounds__(256)
void dot_bb(const u16* __restrict__ A, const u16* __restrict__ B, int n,
            float* __restrict__ slot) {
    int t = threadIdx.x;
    float local = 0.f;
    for (int i = blockIdx.x * 256 + t; i < n; i += gridDim.x * 256)
        local += b2f(A[i]) * b2f(B[i]);
    __shared__ float buf[256];
    float tot = block_sum(local, buf);
    if (t == 0) atomicAdd(slot, tot);
}

__global__ __launch_bounds__(256)
void sumsq(const float* __restrict__ p, int n, float* __restrict__ slot) {
    int t = threadIdx.x;
    float local = 0.f;
    for (int i = blockIdx.x * 256 + t; i < n; i += gridDim.x * 256) {
        float v = p[i]; local += v * v;
    }
    __shared__ float buf[256];
    float tot = block_sum(local, buf);
    if (t == 0) atomicAdd(slot, tot);
}

// slots: 0 marg, 1 sail, 2 exp, 3 imp, 4 ot, 5 norm1, 6 norm2, 7 dot, 8 gw1, 9 gw2, 10 sandwich
__global__ void combine(const float* __restrict__ s, float* __restrict__ out) {
    if (threadIdx.x == 0 && blockIdx.x == 0) {
        float Np = 2048.f;
        float Nu2 = 4096.f * 4096.f;
        float total = s[0]
                    + s[1] / (Np * Np)
                    + s[2] / Np
                    - s[3] / Np
                    + s[4]
                    + (s[5] + s[6] - 2.f * s[7]) / Nu2
                    + s[8] + s[9] - 2.f * s[10];
        out[0] = total;
    }
}

// ------------------------------------------------------------------
extern "C" void kernel_launch(void* const* d_in, const int* in_sizes, int n_in,
                              void* d_out, int out_size, void* d_ws, size_t ws_size,
                              hipStream_t stream) {
    const float* fXp_in = (const float*)d_in[0];   // 2048 x 256
    const float* fYp_in = (const float*)d_in[1];   // 2048 x 256
    const float* X_in   = (const float*)d_in[2];   // 4096 x 768
    const float* Y_in   = (const float*)d_in[3];   // 4096 x 512
    const float* fX_in  = (const float*)d_in[4];   // 4096 x 256
    const float* fY_in  = (const float*)d_in[5];   // 4096 x 256
    const float* Xa_in  = (const float*)d_in[6];   // 4096 x 768
    const float* Ya_in  = (const float*)d_in[7];   // 4096 x 512
    float* out = (float*)d_out;

    char* w = (char*)d_ws;
    size_t off = 0;
    auto alloc = [&](size_t bytes) -> char* {
        char* p = w + off;
        off += (bytes + 255) & ~(size_t)255;
        return p;
    };

    const size_t N = 4096, Np = 2048, DX = 768, DY = 512, DF = 256;

    // ---- five shared 32 MB N x N slots (lifetime-scheduled) ----
    const size_t SLOT = N * N * 2;
    char* S1 = alloc(SLOT);
    char* S2 = alloc(SLOT);
    char* S3 = alloc(SLOT);
    char* S4 = alloc(SLOT);
    char* S5 = alloc(SLOT);

    // S1: Xa -> Cu -> T1T(bf16)
    u16* Xa   = (u16*)S1;
    u16* Cu   = (u16*)S1;
    u16* T1T  = (u16*)S1;
    // S2: Ya -> CuT
    u16* Ya   = (u16*)S2;
    u16* CuT  = (u16*)S2;
    // S3: Ca -> XsT + W1S + W2S
    u16* Ca   = (u16*)S3;
    u16* XsT  = (u16*)S3;                          // 6 MB
    float* W1S = (float*)(S3 + 8 * 1024 * 1024);   // 4 x 2.36 MB
    float* W2S = (float*)(S3 + 20 * 1024 * 1024);  // 4 x 1.05 MB
    // S4: XaT+YaT -> XS -> XnT+YnT -> CaT -> T1S (4 slices x 8 MB = 32 MB)
    u16* XaT  = (u16*)S4;
    u16* YaT  = (u16*)(S4 + N * DX * 2);
    float* XS = (float*)S4;
    u16* XnT  = (u16*)S4;
    u16* YnT  = (u16*)(S4 + N * DX * 2);
    u16* CaT  = (u16*)S4;
    float* T1S= (float*)S4;
    // S5: YS -> Tb -> plan
    float* YS = (float*)S5;
    u16* Tb   = (u16*)S5;
    u16* plan = (u16*)S5;

    // ---- dedicated bf16 buffers ----
    u16* fXp  = (u16*)alloc(Np * DF * 2);
    u16* fYp  = (u16*)alloc(Np * DF * 2);
    u16* fXn  = (u16*)alloc(N * DF * 2);
    u16* fYn  = (u16*)alloc(N * DF * 2);
    u16* fXnT = (u16*)alloc(N * DF * 2);
    u16* fYnT = (u16*)alloc(N * DF * 2);
    u16* Xu   = (u16*)alloc(N * DX * 2);
    u16* Yu   = (u16*)alloc(N * DY * 2);
    u16* Xn   = (u16*)alloc(N * DX * 2);
    u16* Yn   = (u16*)alloc(N * DY * 2);
    u16* XuT  = (u16*)alloc(N * DX * 2);   // hoisted: depends only on Xu
    u16* YuT  = (u16*)alloc(N * DY * 2);   // hoisted: depends only on Yu
    u16* Sxx  = (u16*)alloc(DX * DX * 2);
    u16* Syy  = (u16*)alloc(DY * DY * 2);
    u16* SxyT = (u16*)alloc(DY * DX * 2);
    u16* Gx   = (u16*)alloc(DX * DX * 2);
    u16* Gy   = (u16*)alloc(DY * DY * 2);
    u16* Gfx  = (u16*)alloc(DF * DF * 2);
    u16* Gfy  = (u16*)alloc(DF * DF * 2);
    u16* A1b  = (u16*)alloc(DX * DF * 2);
    u16* B1Tb = (u16*)alloc(DY * DF * 2);
    u16* Hb   = (u16*)alloc(DX * DY * 2);
    u16* cosp = (u16*)alloc(Np * Np * 2);
    u16* cospT= (u16*)alloc(Np * Np * 2);
    float* ap = (float*)alloc(Np * 4);
    float* au = (float*)alloc(N * 4);

    // ---- zero zone (ONE memset): slots + potentials + fp32 atomic targets ----
    char* zero_begin = w + off;
    float* slots = (float*)alloc(64 * 4);
    float* up = (float*)alloc(Np * 4);
    float* vp = (float*)alloc(Np * 4);
    float* uu = (float*)alloc(N * 4);
    float* vu = (float*)alloc(N * 4);
    float* ua = (float*)alloc(N * 4);
    float* va = (float*)alloc(N * 4);
    float* SxxF  = (float*)alloc(DX * DX * 4);
    float* SyyF  = (float*)alloc(DY * DY * 4);
    float* SxyTF = (float*)alloc(DY * DX * 4);
    float* GxF   = (float*)alloc(DX * DX * 4);
    float* GyF   = (float*)alloc(DY * DY * 4);
    float* GfxF  = (float*)alloc(DF * DF * 4);
    float* GfyF  = (float*)alloc(DF * DF * 4);
    float* A1F   = (float*)alloc(DX * DF * 4);
    float* B1F   = (float*)alloc(DY * DF * 4);
    float* HbF   = (float*)alloc(DX * DY * 4);
    float* MF    = (float*)alloc(DX * DY * 4);
    size_t zero_bytes = (size_t)((w + off) - zero_begin);

    const float SCALE = 20.f;   // 1/eps
    const float LM12 = -logf(4096.f), LM3 = -logf(2048.f);

    hipMemsetAsync(zero_begin, 0, zero_bytes, stream);

    // ===== 1. all row-normalizations (one dispatch) =====
    {
        RNArgs a;
        a.d[0] = {Xa_in, Xa, 768, 4096};
        a.d[1] = {Ya_in, Ya, 512, 8192};
        a.d[2] = {fXp_in, fXp, 256, 10240};
        a.d[3] = {fYp_in, fYp, 256, 12288};
        a.d[4] = {fX_in, fXn, 256, 16384};
        a.d[5] = {fY_in, fYn, 256, 20480};
        a.d[6] = {X_in, Xu, 768, 24576};
        a.d[7] = {Y_in, Yu, 512, 28672};
        a.n = 8;
        rownorm_batch<<<7168, 256, 0, stream>>>(a);
    }

    // ===== 2. transposes A: XaT, YaT, fXnT, fYnT + hoisted XuT, YuT =====
    {
        TPArgs a;
        a.d[0] = {Xa, XaT, 4096, 768, 24, 3072, nullptr};
        a.d[1] = {Ya, YaT, 4096, 512, 16, 5120, nullptr};
        a.d[2] = {fXn, fXnT, 4096, 256, 8, 6144, nullptr};
        a.d[3] = {fYn, fYnT, 4096, 256, 8, 7168, nullptr};
        a.d[4] = {Xu, XuT, 4096, 768, 24, 10240, nullptr};
        a.d[5] = {Yu, YuT, 4096, 512, 16, 12288, nullptr};
        a.n = 6;
        transpose_batch<<<12288, 256, 0, stream>>>(a);
    }

    // ===== 3. batch1: anchor covariances (split-K8, atomic) + cast =====
    {
        BGNArgs g;
        g.d[0] = {XaT, XaT, SxxF, nullptr, nullptr, nullptr, 768, 768, 512, 4096, 0, 6, 36};
        g.d[1] = {YaT, YaT, SyyF, nullptr, nullptr, nullptr, 512, 512, 512, 4096, 0, 4, 52};
        g.d[2] = {YaT, XaT, SxyTF, nullptr, nullptr, nullptr, 512, 768, 512, 4096, 0, 6, 76};
        g.n = 3; g.alpha = 1.f / 4096.f;
        bgemmN<3><<<dim3(76, 8), 256, 0, stream>>>(g);
        cast_f2b<<<256, 256, 0, stream>>>(SxxF, Sxx, 768 * 768 + 512 * 512 + 512 * 768);
    }

    // ===== 4. Mahalanobis: XS/YS in one batched dispatch =====
    {
        BGNArgs g;
        g.d[0] = {Xu, Sxx, XS, nullptr, nullptr, nullptr, 4096, 768, 768, 768, 0, 6, 192};
        g.d[1] = {Yu, Syy, YS, nullptr, nullptr, nullptr, 4096, 512, 512, 512, 0, 4, 320};
        g.n = 2; g.alpha = 1.f;
        bgemmN<0><<<dim3(320, 1), 256, 0, stream>>>(g);
    }
    mahal_w<<<1024, 256, 0, stream>>>(Xu, XS, Xn, 4096, 768);
    mahal_w<<<1024, 256, 0, stream>>>(Yu, YS, Yn, 4096, 512);

    // ===== 5. transposes B: XnT, YnT (clobber XS in S4) =====
    {
        TPArgs a;
        a.d[0] = {Xn, XnT, 4096, 768, 24, 3072, nullptr};
        a.d[1] = {Yn, YnT, 4096, 512, 16, 5120, nullptr};
        a.n = 2;
        transpose_batch<<<5120, 256, 0, stream>>>(a);
    }

    // ===== 6. batch2: L_div gram matrices (split-K8, atomic) + cast =====
    {
        BGNArgs g;
        g.d[0] = {XnT, XnT, GxF, nullptr, nullptr, nullptr, 768, 768, 512, 4096, 0, 6, 36};
        g.d[1] = {YnT, YnT, GyF, nullptr, nullptr, nullptr, 512, 512, 512, 4096, 0, 4, 52};
        g.d[2] = {fXnT, fXnT, GfxF, nullptr, nullptr, nullptr, 256, 256, 512, 4096, 0, 2, 56};
        g.d[3] = {fYnT, fYnT, GfyF, nullptr, nullptr, nullptr, 256, 256, 512, 4096, 0, 2, 60};
        g.d[4] = {XnT, fXnT, A1F, nullptr, nullptr, nullptr, 768, 256, 512, 4096, 0, 2, 72};
        g.d[5] = {YnT, fYnT, B1F, nullptr, nullptr, nullptr, 512, 256, 512, 4096, 0, 2, 80};
        g.n = 6; g.alpha = 1.f;
        bgemmN<3><<<dim3(80, 8), 256, 0, stream>>>(g);
        cast_f2b<<<256, 256, 0, stream>>>(GxF, Gx,
            768 * 768 + 512 * 512 + 256 * 256 + 256 * 256 + 768 * 256 + 512 * 256);
    }

    // ===== 7. cost matrices Cu, cosp, Tb in ONE batched bf16 dispatch =====
    {
        BGNArgs g;
        g.d[0] = {fXn, fYn, nullptr, Cu, nullptr, nullptr, 4096, 4096, 256, 256, 0, 32, 1024};
        g.d[1] = {fXp, fYp, nullptr, cosp, nullptr, nullptr, 2048, 2048, 256, 256, 0, 16, 1280};
        g.d[2] = {Xn, SxyT, nullptr, Tb, nullptr, nullptr, 4096, 512, 768, 768, 0, 4, 1408};
        g.n = 3; g.alpha = 1.f;
        bgemmN<1><<<dim3(1408, 1), 256, 0, stream>>>(g);
    }
    gemm_bt<1><<<dim3(32, 32), 256, 0, stream>>>(Tb, Yn, nullptr, Ca, 4096, 4096, 512, 512, 1.f);

    // ===== 8. transposes C: CuT, cospT, CaT =====
    {
        TPArgs a;
        a.d[0] = {Cu, CuT, 4096, 4096, 128, 16384, nullptr};
        a.d[1] = {cosp, cospT, 2048, 2048, 64, 20480, nullptr};
        a.d[2] = {Ca, CaT, 4096, 4096, 128, 36864, nullptr};
        a.n = 3;
        transpose_batch<<<36864, 256, 0, stream>>>(a);
    }

    // ===== 9. L_div tail =====
    gemm_bt<3><<<dim3(4, 6, 4), 256, 0, stream>>>(Gx, SxyT, HbF, nullptr, 768, 512, 192, 768, 1.f);
    cast_f2b<<<256, 256, 0, stream>>>(HbF, Hb, 768 * 512);
    {
        BGNArgs g;
        g.d[0] = {Hb, Gy, nullptr, nullptr, SxyT, slots + 5, 768, 512, 128, 512, 768, 4, 24};
        g.d[1] = {A1b, B1Tb, nullptr, nullptr, SxyT, slots + 7, 768, 512, 64, 256, 768, 4, 48};
        g.n = 2; g.alpha = 1.f;
        bgemmN<2><<<dim3(48, 4), 256, 0, stream>>>(g);
    }
    dot_bb<<<64, 256, 0, stream>>>(Gfx, Gfy, 256 * 256, slots + 6);

    // ===== 10. triple-fused sinkhorn, 10 iters (dispatch path — coop grid.sync
    //           measured 13x slower on 8-XCD MI355X; see round-9 post-mortem) =====
    for (int it = 0; it < 10; ++it) {
        row_lse_tri<<<2560, 256, 0, stream>>>(Cu, vu, uu, Ca, va, ua, cosp, vp, up, SCALE, LM12, LM3);
        row_lse_tri<<<2560, 256, 0, stream>>>(CuT, uu, vu, CaT, ua, va, cospT, up, vp, SCALE, LM12, LM3);
    }

    // ===== 11. fused plan + au + L_ot + pairs rowsums, then fused tails =====
    plan_ot<<<1536, 256, 0, stream>>>(Cu, Ca, cosp, uu, vu, ua, va, up, vp,
                                      plan, au, ap, slots + 4, SCALE);
    tail_fused<<<515, 256, 0, stream>>>(cosp, ap, au, up, vp, SCALE, slots);

    // ===== 12. GW via low-rank identities (slice split-K4 — z=4 is the measured
    //           sweet spot: 720 blocks; z=2 regressed to 62 us, round-10 PM) =====
    {
        TPArgs a;
        a.d[0] = {Xu, XsT, 4096, 768, 24, 3072, au};   // au-scaled transpose (S3; Ca dead)
        a.n = 1;
        transpose_batch<<<3072, 256, 0, stream>>>(a);
    }
    {
        BGNArgs g;
        g.d[0] = {YuT, plan, T1S, nullptr, nullptr, nullptr, 512, 4096, 1024, 4096, 0, 32, 128};
        g.d[1] = {XsT, XuT, W1S, nullptr, nullptr, nullptr, 768, 768, 1024, 4096, 0, 6, 164};
        g.d[2] = {YuT, YuT, W2S, nullptr, nullptr, nullptr, 512, 512, 1024, 4096, 0, 4, 180};
        g.n = 3; g.alpha = 1.f;
        bgemmN<4><<<dim3(180, 4), 256, 0, stream>>>(g);
    }
    gw_reduce<<<564, 256, 0, stream>>>(T1S, T1T, W1S, W2S, slots + 8, slots + 9);
    {
        BGNArgs g;
        g.d[0] = {XuT, T1T, MF, nullptr, nullptr, nullptr, 768, 512, 512, 4096, 0, 4, 24};
        g.n = 1; g.alpha = 1.f;
        bgemmN<3><<<dim3(24, 8), 256, 0, stream>>>(g);
    }
    sumsq<<<32, 256, 0, stream>>>(MF, 768 * 512, slots + 10);

    combine<<<1, 1, 0, stream>>>(slots, out);
}